// Round 1
// baseline (2704.830 us; speedup 1.0000x reference)
//
#include <hip/hip_runtime.h>

#define NN 50000
#define NE 1000000
#define NEP 400000
#define HD 128
#define CD 768

// ---------------- degree / dinv ----------------
__global__ __launch_bounds__(256) void deg_kernel(const int* __restrict__ col,
                                                  float* __restrict__ deg) {
    int i = blockIdx.x * 256 + threadIdx.x;
    if (i < NE) unsafeAtomicAdd(&deg[col[i]], 1.0f);
}

__global__ __launch_bounds__(256) void dinv_kernel(float* __restrict__ deg) {
    int i = blockIdx.x * 256 + threadIdx.x;
    if (i < NN) {
        float d = deg[i];
        deg[i] = (d > 0.0f) ? 1.0f / sqrtf(d) : 0.0f;
    }
}

// ---------------- generic row-tiled fp32 matmul: out(nrows x 128) = A(nrows x K) @ W(K x 128) ----------------
// block: 256 threads; 64 rows per block; thread t: tcol=t&31 -> cols 4*tcol..+3, trow=t>>5 -> rows trow*8..+7
template <int K, bool CHEM_EPI>
__global__ __launch_bounds__(256) void matmul_kernel(const float* __restrict__ A,
                                                     const float* __restrict__ W,
                                                     const float* __restrict__ bias,
                                                     const float* __restrict__ mask,
                                                     float* __restrict__ out,
                                                     int nrows) {
    __shared__ float Alds[64][64];
    __shared__ float Wlds[64][128];
    const int t = threadIdx.x;
    const int tcol = t & 31, trow = t >> 5;
    const int rowBase = blockIdx.x * 64;

    float4 acc[8];
#pragma unroll
    for (int r = 0; r < 8; ++r) acc[r] = make_float4(0.f, 0.f, 0.f, 0.f);

    for (int kc = 0; kc < K; kc += 64) {
        // stage A chunk (64 rows x 64 k) as float4
#pragma unroll
        for (int it = 0; it < 4; ++it) {
            int li = t + it * 256;          // float4 idx in [0,1024)
            int r = li >> 4, d4 = li & 15;  // row, float4-col within chunk
            int grow = rowBase + r;
            float4 v = make_float4(0.f, 0.f, 0.f, 0.f);
            if (grow < nrows) v = *(const float4*)&A[(size_t)grow * K + kc + d4 * 4];
            ((float4*)&Alds[0][0])[li] = v;
        }
        // stage W chunk (64 k x 128 cols)
#pragma unroll
        for (int it = 0; it < 8; ++it) {
            int li = t + it * 256;  // float4 idx in [0,2048)
            ((float4*)&Wlds[0][0])[li] = ((const float4*)W)[(size_t)kc * 32 + li];
        }
        __syncthreads();
#pragma unroll
        for (int kk = 0; kk < 64; kk += 2) {
            float4 w0 = *(const float4*)&Wlds[kk][tcol * 4];
            float4 w1 = *(const float4*)&Wlds[kk + 1][tcol * 4];
#pragma unroll
            for (int r = 0; r < 8; ++r) {
                float2 a = *(const float2*)&Alds[trow * 8 + r][kk];
                acc[r].x = fmaf(a.x, w0.x, fmaf(a.y, w1.x, acc[r].x));
                acc[r].y = fmaf(a.x, w0.y, fmaf(a.y, w1.y, acc[r].y));
                acc[r].z = fmaf(a.x, w0.z, fmaf(a.y, w1.z, acc[r].z));
                acc[r].w = fmaf(a.x, w0.w, fmaf(a.y, w1.w, acc[r].w));
            }
        }
        __syncthreads();
    }
    // epilogue
    if (CHEM_EPI) {
        float4 b4 = ((const float4*)bias)[tcol];
#pragma unroll
        for (int r = 0; r < 8; ++r) {
            int grow = rowBase + trow * 8 + r;
            if (grow < nrows) {
                float m = mask[grow];
                float4 v;
                v.x = fmaxf(acc[r].x + b4.x, 0.f) * m;
                v.y = fmaxf(acc[r].y + b4.y, 0.f) * m;
                v.z = fmaxf(acc[r].z + b4.z, 0.f) * m;
                v.w = fmaxf(acc[r].w + b4.w, 0.f) * m;
                ((float4*)out)[(size_t)grow * 32 + tcol] = v;
            }
        }
    } else {
#pragma unroll
        for (int r = 0; r < 8; ++r) {
            int grow = rowBase + trow * 8 + r;
            if (grow < nrows) ((float4*)out)[(size_t)grow * 32 + tcol] = acc[r];
        }
    }
}

// ---------------- message passing: agg[col] += h[row] * dinv[row]*dinv[col] ----------------
// one wave (64 lanes) per edge, float2 per lane
__global__ __launch_bounds__(256) void message_kernel(const int* __restrict__ row,
                                                      const int* __restrict__ col,
                                                      const float* __restrict__ dinv,
                                                      const float* __restrict__ h,
                                                      float* __restrict__ agg) {
    int wid = blockIdx.x * 4 + (threadIdx.x >> 6);
    int lane = threadIdx.x & 63;
    if (wid >= NE) return;
    int r = row[wid], cl = col[wid];
    float nrm = dinv[r] * dinv[cl];
    float2 v = *(const float2*)&h[(size_t)r * HD + lane * 2];
    unsafeAtomicAdd(&agg[(size_t)cl * HD + lane * 2 + 0], v.x * nrm);
    unsafeAtomicAdd(&agg[(size_t)cl * HD + lane * 2 + 1], v.y * nrm);
}

// ---------------- z = relu(agg + bias) ----------------
__global__ __launch_bounds__(256) void bias_relu_kernel(float* __restrict__ z,
                                                        const float* __restrict__ bias) {
    int i = blockIdx.x * 256 + threadIdx.x;  // float4 index over NN*128/4
    float4 v = ((float4*)z)[i];
    float4 b = ((const float4*)bias)[i & 31];
    v.x = fmaxf(v.x + b.x, 0.f);
    v.y = fmaxf(v.y + b.y, 0.f);
    v.z = fmaxf(v.z + b.z, 0.f);
    v.w = fmaxf(v.w + b.w, 0.f);
    ((float4*)z)[i] = v;
}

// ---------------- decoder: per block 64 edges; F(64x256) gathered on the fly ----------------
__global__ __launch_bounds__(256) void decode_kernel(const int* __restrict__ edges,
                                                     const float* __restrict__ z,
                                                     const float* __restrict__ c,
                                                     const float* __restrict__ W1,
                                                     const float* __restrict__ b1,
                                                     const float* __restrict__ W2,
                                                     const float* __restrict__ b2,
                                                     float* __restrict__ out) {
    __shared__ float Flds[64][64];
    __shared__ float Wlds[64][128];
    __shared__ int sEdge[128];
    const int t = threadIdx.x;
    const int tcol = t & 31, trow = t >> 5;
    const int ebase = blockIdx.x * 64;

    if (t < 128) sEdge[t] = edges[(size_t)ebase * 2 + t];
    __syncthreads();

    float4 acc[8];
#pragma unroll
    for (int r = 0; r < 8; ++r) acc[r] = make_float4(0.f, 0.f, 0.f, 0.f);

    for (int ic = 0; ic < 4; ++ic) {
        // stage F chunk: chunk ic covers f dims ic*64..ic*64+63
        const float4* src4 = (const float4*)((ic < 2) ? z : c);
        const int d4base = (ic & 1) ? 16 : 0;
#pragma unroll
        for (int it = 0; it < 4; ++it) {
            int li = t + it * 256;          // float4 idx in [0,1024)
            int e = li >> 4, d4 = li & 15;
            int s = sEdge[e * 2], dd = sEdge[e * 2 + 1];
            float4 a4 = src4[(size_t)s * 32 + d4base + d4];
            float4 b4 = src4[(size_t)dd * 32 + d4base + d4];
            float4 v;
            v.x = a4.x * b4.x;
            v.y = a4.y * b4.y;
            v.z = a4.z * b4.z;
            v.w = a4.w * b4.w;
            ((float4*)&Flds[0][0])[li] = v;
        }
        // stage W1 chunk
#pragma unroll
        for (int it = 0; it < 8; ++it) {
            int li = t + it * 256;
            ((float4*)&Wlds[0][0])[li] = ((const float4*)W1)[(size_t)ic * 2048 + li];
        }
        __syncthreads();
#pragma unroll
        for (int kk = 0; kk < 64; kk += 2) {
            float4 w0 = *(const float4*)&Wlds[kk][tcol * 4];
            float4 w1 = *(const float4*)&Wlds[kk + 1][tcol * 4];
#pragma unroll
            for (int r = 0; r < 8; ++r) {
                float2 a = *(const float2*)&Flds[trow * 8 + r][kk];
                acc[r].x = fmaf(a.x, w0.x, fmaf(a.y, w1.x, acc[r].x));
                acc[r].y = fmaf(a.x, w0.y, fmaf(a.y, w1.y, acc[r].y));
                acc[r].z = fmaf(a.x, w0.z, fmaf(a.y, w1.z, acc[r].z));
                acc[r].w = fmaf(a.x, w0.w, fmaf(a.y, w1.w, acc[r].w));
            }
        }
        __syncthreads();
    }

    // epilogue: hmid = relu(acc + b1); out = hmid @ W2 + b2
    float4 b1v = ((const float4*)b1)[tcol];
    float4 w2v = ((const float4*)W2)[tcol];
    float b2v = b2[0];
#pragma unroll
    for (int r = 0; r < 8; ++r) {
        float4 h4;
        h4.x = fmaxf(acc[r].x + b1v.x, 0.f);
        h4.y = fmaxf(acc[r].y + b1v.y, 0.f);
        h4.z = fmaxf(acc[r].z + b1v.z, 0.f);
        h4.w = fmaxf(acc[r].w + b1v.w, 0.f);
        float p = h4.x * w2v.x + h4.y * w2v.y + h4.z * w2v.z + h4.w * w2v.w;
#pragma unroll
        for (int m = 16; m >= 1; m >>= 1) p += __shfl_xor(p, m);
        if (tcol == 0) out[ebase + trow * 8 + r] = p + b2v;
    }
}

extern "C" void kernel_launch(void* const* d_in, const int* in_sizes, int n_in,
                              void* d_out, int out_size, void* d_ws, size_t ws_size,
                              hipStream_t stream) {
    const int* edge_index = (const int*)d_in[0];
    const float* chemistry = (const float*)d_in[1];
    const int* pos_edge = (const int*)d_in[2];
    const int* neg_edge = (const int*)d_in[3];
    const float* smiles_mask = (const float*)d_in[4];
    const float* node_emb = (const float*)d_in[5];
    const float* conv_w = (const float*)d_in[6];
    const float* conv_b = (const float*)d_in[7];
    const float* chem_w = (const float*)d_in[8];
    const float* chem_b = (const float*)d_in[9];
    const float* dec_w1 = (const float*)d_in[10];
    const float* dec_b1 = (const float*)d_in[11];
    const float* dec_w2 = (const float*)d_in[12];
    const float* dec_b2 = (const float*)d_in[13];
    float* out = (float*)d_out;

    char* ws = (char*)d_ws;
    const size_t NH_BYTES = (size_t)NN * HD * 4;  // 25.6 MB
    float* dinv = (float*)ws;                                // 200 KB (padded)
    float* bufA = (float*)(ws + 204800);                     // z / agg
    float* bufH = (float*)(ws + 204800 + NH_BYTES);          // h
    float* bufC = (float*)(ws + 204800 + 2 * NH_BYTES);      // c

    const int* e_row = edge_index;
    const int* e_col = edge_index + NE;

    // degree -> dinv
    hipMemsetAsync(dinv, 0, (size_t)NN * 4, stream);
    deg_kernel<<<(NE + 255) / 256, 256, 0, stream>>>(e_col, dinv);
    dinv_kernel<<<(NN + 255) / 256, 256, 0, stream>>>(dinv);

    const int mmGrid = (NN + 63) / 64;

    // layer 0
    matmul_kernel<HD, false><<<mmGrid, 256, 0, stream>>>(node_emb, conv_w, nullptr, nullptr, bufH, NN);
    hipMemsetAsync(bufA, 0, NH_BYTES, stream);
    message_kernel<<<NE / 4, 256, 0, stream>>>(e_row, e_col, dinv, bufH, bufA);
    bias_relu_kernel<<<NN * HD / 4 / 256, 256, 0, stream>>>(bufA, conv_b);

    // layer 1
    matmul_kernel<HD, false><<<mmGrid, 256, 0, stream>>>(bufA, conv_w + HD * HD, nullptr, nullptr, bufH, NN);
    hipMemsetAsync(bufA, 0, NH_BYTES, stream);
    message_kernel<<<NE / 4, 256, 0, stream>>>(e_row, e_col, dinv, bufH, bufA);
    bias_relu_kernel<<<NN * HD / 4 / 256, 256, 0, stream>>>(bufA, conv_b + HD);

    // chemistry features
    matmul_kernel<CD, true><<<mmGrid, 256, 0, stream>>>(chemistry, chem_w, chem_b, smiles_mask, bufC, NN);

    // decode pos / neg
    decode_kernel<<<NEP / 64, 256, 0, stream>>>(pos_edge, bufA, bufC, dec_w1, dec_b1, dec_w2, dec_b2, out);
    decode_kernel<<<NEP / 64, 256, 0, stream>>>(neg_edge, bufA, bufC, dec_w1, dec_b1, dec_w2, dec_b2, out + NEP);
}

// Round 2
// 1160.437 us; speedup vs baseline: 2.3309x; 2.3309x over previous
//
#include <hip/hip_runtime.h>

#define NN 50000
#define NE 1000000
#define NEP 400000
#define HD 128
#define CD 768
#define NB_SCAN 196  // ceil(NN/256)

// ---------------- CSR build ----------------
__global__ __launch_bounds__(256) void count_kernel(const int* __restrict__ col,
                                                    int* __restrict__ cnt) {
    int i = blockIdx.x * 256 + threadIdx.x;
    if (i < NE) atomicAdd(&cnt[col[i]], 1);
}

__global__ __launch_bounds__(256) void dinv_kernel(const int* __restrict__ cnt,
                                                   float* __restrict__ dinv) {
    int i = blockIdx.x * 256 + threadIdx.x;
    if (i < NN) {
        int d = cnt[i];
        dinv[i] = (d > 0) ? 1.0f / sqrtf((float)d) : 0.0f;
    }
}

// per-block exclusive scan of cnt -> partial, block totals -> bsum
__global__ __launch_bounds__(256) void scan1_kernel(const int* __restrict__ cnt,
                                                    int* __restrict__ partial,
                                                    int* __restrict__ bsum) {
    __shared__ int s[256];
    int i = blockIdx.x * 256 + threadIdx.x;
    int v = (i < NN) ? cnt[i] : 0;
    s[threadIdx.x] = v;
    __syncthreads();
    for (int o = 1; o < 256; o <<= 1) {
        int t = (threadIdx.x >= o) ? s[threadIdx.x - o] : 0;
        __syncthreads();
        s[threadIdx.x] += t;
        __syncthreads();
    }
    if (i < NN) partial[i] = s[threadIdx.x] - v;
    if (threadIdx.x == 255) bsum[blockIdx.x] = s[255];
}

// single-block exclusive scan of block sums (NB_SCAN <= 256)
__global__ __launch_bounds__(256) void scan2_kernel(int* __restrict__ bsum) {
    __shared__ int s[256];
    int v = (threadIdx.x < NB_SCAN) ? bsum[threadIdx.x] : 0;
    s[threadIdx.x] = v;
    __syncthreads();
    for (int o = 1; o < 256; o <<= 1) {
        int t = (threadIdx.x >= o) ? s[threadIdx.x - o] : 0;
        __syncthreads();
        s[threadIdx.x] += t;
        __syncthreads();
    }
    if (threadIdx.x < NB_SCAN) bsum[threadIdx.x] = s[threadIdx.x] - v;
}

__global__ __launch_bounds__(256) void scan3_kernel(const int* __restrict__ partial,
                                                    const int* __restrict__ bsum,
                                                    int* __restrict__ off,
                                                    int* __restrict__ cursor) {
    int i = blockIdx.x * 256 + threadIdx.x;
    if (i < NN) {
        int o = partial[i] + bsum[blockIdx.x];
        off[i] = o;
        cursor[i] = o;
    }
}

__global__ __launch_bounds__(256) void fill_kernel(const int* __restrict__ row,
                                                   const int* __restrict__ col,
                                                   const float* __restrict__ dinv,
                                                   int* __restrict__ cursor,
                                                   int* __restrict__ csr_idx,
                                                   float* __restrict__ csr_w) {
    int e = blockIdx.x * 256 + threadIdx.x;
    if (e < NE) {
        int c = col[e], r = row[e];
        int slot = atomicAdd(&cursor[c], 1);
        csr_idx[slot] = r;
        csr_w[slot] = dinv[r];
    }
}

// ---------------- generic row-tiled fp32 matmul: out(nrows x 128) = A(nrows x K) @ W(K x 128) ----------------
template <int K, bool CHEM_EPI>
__global__ __launch_bounds__(256) void matmul_kernel(const float* __restrict__ A,
                                                     const float* __restrict__ W,
                                                     const float* __restrict__ bias,
                                                     const float* __restrict__ mask,
                                                     float* __restrict__ out,
                                                     int nrows) {
    __shared__ float Alds[64][64];
    __shared__ float Wlds[64][128];
    const int t = threadIdx.x;
    const int tcol = t & 31, trow = t >> 5;
    const int rowBase = blockIdx.x * 64;

    float4 acc[8];
#pragma unroll
    for (int r = 0; r < 8; ++r) acc[r] = make_float4(0.f, 0.f, 0.f, 0.f);

    for (int kc = 0; kc < K; kc += 64) {
#pragma unroll
        for (int it = 0; it < 4; ++it) {
            int li = t + it * 256;
            int r = li >> 4, d4 = li & 15;
            int grow = rowBase + r;
            float4 v = make_float4(0.f, 0.f, 0.f, 0.f);
            if (grow < nrows) v = *(const float4*)&A[(size_t)grow * K + kc + d4 * 4];
            ((float4*)&Alds[0][0])[li] = v;
        }
#pragma unroll
        for (int it = 0; it < 8; ++it) {
            int li = t + it * 256;
            ((float4*)&Wlds[0][0])[li] = ((const float4*)W)[(size_t)kc * 32 + li];
        }
        __syncthreads();
#pragma unroll
        for (int kk = 0; kk < 64; kk += 2) {
            float4 w0 = *(const float4*)&Wlds[kk][tcol * 4];
            float4 w1 = *(const float4*)&Wlds[kk + 1][tcol * 4];
#pragma unroll
            for (int r = 0; r < 8; ++r) {
                float2 a = *(const float2*)&Alds[trow * 8 + r][kk];
                acc[r].x = fmaf(a.x, w0.x, fmaf(a.y, w1.x, acc[r].x));
                acc[r].y = fmaf(a.x, w0.y, fmaf(a.y, w1.y, acc[r].y));
                acc[r].z = fmaf(a.x, w0.z, fmaf(a.y, w1.z, acc[r].z));
                acc[r].w = fmaf(a.x, w0.w, fmaf(a.y, w1.w, acc[r].w));
            }
        }
        __syncthreads();
    }
    if (CHEM_EPI) {
        float4 b4 = ((const float4*)bias)[tcol];
#pragma unroll
        for (int r = 0; r < 8; ++r) {
            int grow = rowBase + trow * 8 + r;
            if (grow < nrows) {
                float m = mask[grow];
                float4 v;
                v.x = fmaxf(acc[r].x + b4.x, 0.f) * m;
                v.y = fmaxf(acc[r].y + b4.y, 0.f) * m;
                v.z = fmaxf(acc[r].z + b4.z, 0.f) * m;
                v.w = fmaxf(acc[r].w + b4.w, 0.f) * m;
                ((float4*)out)[(size_t)grow * 32 + tcol] = v;
            }
        }
    } else {
#pragma unroll
        for (int r = 0; r < 8; ++r) {
            int grow = rowBase + trow * 8 + r;
            if (grow < nrows) ((float4*)out)[(size_t)grow * 32 + tcol] = acc[r];
        }
    }
}

// ---------------- CSR pull aggregation, fused bias+relu+dinv scale ----------------
// one wave per node; lane holds dims lane*2, lane*2+1
__global__ __launch_bounds__(256) void gather_kernel(const int* __restrict__ off,
                                                     const int* __restrict__ cnt,
                                                     const int* __restrict__ csr_idx,
                                                     const float* __restrict__ csr_w,
                                                     const float* __restrict__ dinv,
                                                     const float* __restrict__ h,
                                                     const float* __restrict__ bias,
                                                     float* __restrict__ z) {
    int v = blockIdx.x * 4 + (threadIdx.x >> 6);
    if (v >= NN) return;
    int lane = threadIdx.x & 63;
    int s = off[v];
    int e = s + cnt[v];
    float accx = 0.f, accy = 0.f;
    for (; s + 3 < e; s += 4) {
        int r0 = csr_idx[s], r1 = csr_idx[s + 1], r2 = csr_idx[s + 2], r3 = csr_idx[s + 3];
        float w0 = csr_w[s], w1 = csr_w[s + 1], w2 = csr_w[s + 2], w3 = csr_w[s + 3];
        float2 h0 = *(const float2*)&h[(size_t)r0 * HD + lane * 2];
        float2 h1 = *(const float2*)&h[(size_t)r1 * HD + lane * 2];
        float2 h2 = *(const float2*)&h[(size_t)r2 * HD + lane * 2];
        float2 h3 = *(const float2*)&h[(size_t)r3 * HD + lane * 2];
        accx = fmaf(h0.x, w0, accx); accy = fmaf(h0.y, w0, accy);
        accx = fmaf(h1.x, w1, accx); accy = fmaf(h1.y, w1, accy);
        accx = fmaf(h2.x, w2, accx); accy = fmaf(h2.y, w2, accy);
        accx = fmaf(h3.x, w3, accx); accy = fmaf(h3.y, w3, accy);
    }
    for (; s < e; ++s) {
        int r0 = csr_idx[s];
        float w0 = csr_w[s];
        float2 h0 = *(const float2*)&h[(size_t)r0 * HD + lane * 2];
        accx = fmaf(h0.x, w0, accx); accy = fmaf(h0.y, w0, accy);
    }
    float dv = dinv[v];
    float2 b = *(const float2*)&bias[lane * 2];
    float2 o;
    o.x = fmaxf(fmaf(accx, dv, b.x), 0.f);
    o.y = fmaxf(fmaf(accy, dv, b.y), 0.f);
    *(float2*)&z[(size_t)v * HD + lane * 2] = o;
}

// ---------------- decoder ----------------
__global__ __launch_bounds__(256) void decode_kernel(const int* __restrict__ edges,
                                                     const float* __restrict__ z,
                                                     const float* __restrict__ c,
                                                     const float* __restrict__ W1,
                                                     const float* __restrict__ b1,
                                                     const float* __restrict__ W2,
                                                     const float* __restrict__ b2,
                                                     float* __restrict__ out) {
    __shared__ float Flds[64][64];
    __shared__ float Wlds[64][128];
    __shared__ int sEdge[128];
    const int t = threadIdx.x;
    const int tcol = t & 31, trow = t >> 5;
    const int ebase = blockIdx.x * 64;

    if (t < 128) sEdge[t] = edges[(size_t)ebase * 2 + t];
    __syncthreads();

    float4 acc[8];
#pragma unroll
    for (int r = 0; r < 8; ++r) acc[r] = make_float4(0.f, 0.f, 0.f, 0.f);

    for (int ic = 0; ic < 4; ++ic) {
        const float4* src4 = (const float4*)((ic < 2) ? z : c);
        const int d4base = (ic & 1) ? 16 : 0;
#pragma unroll
        for (int it = 0; it < 4; ++it) {
            int li = t + it * 256;
            int e = li >> 4, d4 = li & 15;
            int s = sEdge[e * 2], dd = sEdge[e * 2 + 1];
            float4 a4 = src4[(size_t)s * 32 + d4base + d4];
            float4 b4 = src4[(size_t)dd * 32 + d4base + d4];
            float4 v;
            v.x = a4.x * b4.x;
            v.y = a4.y * b4.y;
            v.z = a4.z * b4.z;
            v.w = a4.w * b4.w;
            ((float4*)&Flds[0][0])[li] = v;
        }
#pragma unroll
        for (int it = 0; it < 8; ++it) {
            int li = t + it * 256;
            ((float4*)&Wlds[0][0])[li] = ((const float4*)W1)[(size_t)ic * 2048 + li];
        }
        __syncthreads();
#pragma unroll
        for (int kk = 0; kk < 64; kk += 2) {
            float4 w0 = *(const float4*)&Wlds[kk][tcol * 4];
            float4 w1 = *(const float4*)&Wlds[kk + 1][tcol * 4];
#pragma unroll
            for (int r = 0; r < 8; ++r) {
                float2 a = *(const float2*)&Flds[trow * 8 + r][kk];
                acc[r].x = fmaf(a.x, w0.x, fmaf(a.y, w1.x, acc[r].x));
                acc[r].y = fmaf(a.x, w0.y, fmaf(a.y, w1.y, acc[r].y));
                acc[r].z = fmaf(a.x, w0.z, fmaf(a.y, w1.z, acc[r].z));
                acc[r].w = fmaf(a.x, w0.w, fmaf(a.y, w1.w, acc[r].w));
            }
        }
        __syncthreads();
    }

    float4 b1v = ((const float4*)b1)[tcol];
    float4 w2v = ((const float4*)W2)[tcol];
    float b2v = b2[0];
#pragma unroll
    for (int r = 0; r < 8; ++r) {
        float4 h4;
        h4.x = fmaxf(acc[r].x + b1v.x, 0.f);
        h4.y = fmaxf(acc[r].y + b1v.y, 0.f);
        h4.z = fmaxf(acc[r].z + b1v.z, 0.f);
        h4.w = fmaxf(acc[r].w + b1v.w, 0.f);
        float p = h4.x * w2v.x + h4.y * w2v.y + h4.z * w2v.z + h4.w * w2v.w;
#pragma unroll
        for (int m = 16; m >= 1; m >>= 1) p += __shfl_xor(p, m);
        if (tcol == 0) out[ebase + trow * 8 + r] = p + b2v;
    }
}

extern "C" void kernel_launch(void* const* d_in, const int* in_sizes, int n_in,
                              void* d_out, int out_size, void* d_ws, size_t ws_size,
                              hipStream_t stream) {
    const int* edge_index = (const int*)d_in[0];
    const float* chemistry = (const float*)d_in[1];
    const int* pos_edge = (const int*)d_in[2];
    const int* neg_edge = (const int*)d_in[3];
    const float* smiles_mask = (const float*)d_in[4];
    const float* node_emb = (const float*)d_in[5];
    const float* conv_w = (const float*)d_in[6];
    const float* conv_b = (const float*)d_in[7];
    const float* chem_w = (const float*)d_in[8];
    const float* chem_b = (const float*)d_in[9];
    const float* dec_w1 = (const float*)d_in[10];
    const float* dec_b1 = (const float*)d_in[11];
    const float* dec_w2 = (const float*)d_in[12];
    const float* dec_b2 = (const float*)d_in[13];
    float* out = (float*)d_out;

    char* ws = (char*)d_ws;
    int* cnt = (int*)(ws + 0);                  // 200 KB
    float* dinv = (float*)(ws + 204800);        // 200 KB
    int* partial = (int*)(ws + 409600);         // 200 KB
    int* off = (int*)(ws + 614400);             // 200 KB
    int* cursor = (int*)(ws + 819200);          // 200 KB
    int* bsum = (int*)(ws + 1024000);           // 1 KB
    int* csr_idx = (int*)(ws + 1048576);        // 4 MB
    float* csr_w = (float*)(ws + 5242880);      // 4 MB
    const size_t NH_BYTES = (size_t)NN * HD * 4;
    float* bufZ = (float*)(ws + 9437184);
    float* bufH = (float*)(ws + 9437184 + NH_BYTES);
    float* bufC = (float*)(ws + 9437184 + 2 * NH_BYTES);

    const int* e_row = edge_index;
    const int* e_col = edge_index + NE;

    // ---- CSR build (once) ----
    hipMemsetAsync(cnt, 0, (size_t)NN * 4, stream);
    count_kernel<<<(NE + 255) / 256, 256, 0, stream>>>(e_col, cnt);
    dinv_kernel<<<(NN + 255) / 256, 256, 0, stream>>>(cnt, dinv);
    scan1_kernel<<<NB_SCAN, 256, 0, stream>>>(cnt, partial, bsum);
    scan2_kernel<<<1, 256, 0, stream>>>(bsum);
    scan3_kernel<<<NB_SCAN, 256, 0, stream>>>(partial, bsum, off, cursor);
    fill_kernel<<<(NE + 255) / 256, 256, 0, stream>>>(e_row, e_col, dinv, cursor, csr_idx, csr_w);

    const int mmGrid = (NN + 63) / 64;
    const int gaGrid = (NN + 3) / 4;

    // layer 0
    matmul_kernel<HD, false><<<mmGrid, 256, 0, stream>>>(node_emb, conv_w, nullptr, nullptr, bufH, NN);
    gather_kernel<<<gaGrid, 256, 0, stream>>>(off, cnt, csr_idx, csr_w, dinv, bufH, conv_b, bufZ);

    // layer 1
    matmul_kernel<HD, false><<<mmGrid, 256, 0, stream>>>(bufZ, conv_w + HD * HD, nullptr, nullptr, bufH, NN);
    gather_kernel<<<gaGrid, 256, 0, stream>>>(off, cnt, csr_idx, csr_w, dinv, bufH, conv_b + HD, bufZ);

    // chemistry features
    matmul_kernel<CD, true><<<mmGrid, 256, 0, stream>>>(chemistry, chem_w, chem_b, smiles_mask, bufC, NN);

    // decode pos / neg
    decode_kernel<<<NEP / 64, 256, 0, stream>>>(pos_edge, bufZ, bufC, dec_w1, dec_b1, dec_w2, dec_b2, out);
    decode_kernel<<<NEP / 64, 256, 0, stream>>>(neg_edge, bufZ, bufC, dec_w1, dec_b1, dec_w2, dec_b2, out + NEP);
}

// Round 3
// 742.076 us; speedup vs baseline: 3.6450x; 1.5638x over previous
//
#include <hip/hip_runtime.h>

#define NN 50000
#define NE 1000000
#define NEP 400000
#define HD 128
#define CD 768
#define NB_SCAN 196  // ceil(NN/256)

typedef __attribute__((ext_vector_type(8))) short bf16x8;
typedef __attribute__((ext_vector_type(4))) float f32x4;

__device__ __forceinline__ ushort f2bf(float x) {
    unsigned u = __float_as_uint(x);
    u += 0x7FFF + ((u >> 16) & 1);  // RNE
    return (ushort)(u >> 16);
}
__device__ __forceinline__ float bf2f(ushort b) {
    return __uint_as_float(((unsigned)b) << 16);
}

// ---------------- CSR build ----------------
__global__ __launch_bounds__(256) void count_kernel(const int* __restrict__ col,
                                                    int* __restrict__ cnt) {
    int i = blockIdx.x * 256 + threadIdx.x;
    if (i < NE) atomicAdd(&cnt[col[i]], 1);
}

__global__ __launch_bounds__(256) void dinv_kernel(const int* __restrict__ cnt,
                                                   float* __restrict__ dinv) {
    int i = blockIdx.x * 256 + threadIdx.x;
    if (i < NN) {
        int d = cnt[i];
        dinv[i] = (d > 0) ? 1.0f / sqrtf((float)d) : 0.0f;
    }
}

__global__ __launch_bounds__(256) void scan1_kernel(const int* __restrict__ cnt,
                                                    int* __restrict__ partial,
                                                    int* __restrict__ bsum) {
    __shared__ int s[256];
    int i = blockIdx.x * 256 + threadIdx.x;
    int v = (i < NN) ? cnt[i] : 0;
    s[threadIdx.x] = v;
    __syncthreads();
    for (int o = 1; o < 256; o <<= 1) {
        int t = (threadIdx.x >= o) ? s[threadIdx.x - o] : 0;
        __syncthreads();
        s[threadIdx.x] += t;
        __syncthreads();
    }
    if (i < NN) partial[i] = s[threadIdx.x] - v;
    if (threadIdx.x == 255) bsum[blockIdx.x] = s[255];
}

__global__ __launch_bounds__(256) void scan2_kernel(int* __restrict__ bsum) {
    __shared__ int s[256];
    int v = (threadIdx.x < NB_SCAN) ? bsum[threadIdx.x] : 0;
    s[threadIdx.x] = v;
    __syncthreads();
    for (int o = 1; o < 256; o <<= 1) {
        int t = (threadIdx.x >= o) ? s[threadIdx.x - o] : 0;
        __syncthreads();
        s[threadIdx.x] += t;
        __syncthreads();
    }
    if (threadIdx.x < NB_SCAN) bsum[threadIdx.x] = s[threadIdx.x] - v;
}

__global__ __launch_bounds__(256) void scan3_kernel(const int* __restrict__ partial,
                                                    const int* __restrict__ bsum,
                                                    int* __restrict__ off,
                                                    int* __restrict__ cursor) {
    int i = blockIdx.x * 256 + threadIdx.x;
    if (i < NN) {
        int o = partial[i] + bsum[blockIdx.x];
        off[i] = o;
        cursor[i] = o;
    }
}

__global__ __launch_bounds__(256) void fill_kernel(const int* __restrict__ row,
                                                   const int* __restrict__ col,
                                                   const float* __restrict__ dinv,
                                                   int* __restrict__ cursor,
                                                   int* __restrict__ csr_idx,
                                                   float* __restrict__ csr_w) {
    int e = blockIdx.x * 256 + threadIdx.x;
    if (e < NE) {
        int c = col[e], r = row[e];
        int slot = atomicAdd(&cursor[c], 1);
        csr_idx[slot] = r;
        csr_w[slot] = dinv[r];
    }
}

// ---------------- W1 -> MFMA B-fragment order, bf16 ----------------
// w1f[((ks*8+nt)*64 + l)*8 + j] = W1[ks*32 + (l>>4)*8 + j][nt*16 + (l&15)]
__global__ __launch_bounds__(256) void w1frag_kernel(const float* __restrict__ w1,
                                                     ushort* __restrict__ w1f) {
    int tid = blockIdx.x * 256 + threadIdx.x;  // [0,4096)
    int ks = tid >> 9, nt = (tid >> 6) & 7, l = tid & 63;
    int kbase = ks * 32 + ((l >> 4) << 3);
    int colq = nt * 16 + (l & 15);
    ushort r[8];
#pragma unroll
    for (int j = 0; j < 8; ++j) r[j] = f2bf(w1[(size_t)(kbase + j) * HD + colq]);
    *(uint4*)&w1f[(size_t)tid * 8] = *(uint4*)r;
}

// ---------------- generic row-tiled fp32 matmul: out(nrows x 128) = A(nrows x K) @ W(K x 128) ----------------
template <int K, bool CHEM_EPI>
__global__ __launch_bounds__(256) void matmul_kernel(const float* __restrict__ A,
                                                     const float* __restrict__ W,
                                                     const float* __restrict__ bias,
                                                     const float* __restrict__ mask,
                                                     float* __restrict__ out,
                                                     ushort* __restrict__ outb,
                                                     int nrows) {
    __shared__ float Alds[64][64];
    __shared__ float Wlds[64][128];
    const int t = threadIdx.x;
    const int tcol = t & 31, trow = t >> 5;
    const int rowBase = blockIdx.x * 64;

    float4 acc[8];
#pragma unroll
    for (int r = 0; r < 8; ++r) acc[r] = make_float4(0.f, 0.f, 0.f, 0.f);

    for (int kc = 0; kc < K; kc += 64) {
#pragma unroll
        for (int it = 0; it < 4; ++it) {
            int li = t + it * 256;
            int r = li >> 4, d4 = li & 15;
            int grow = rowBase + r;
            float4 v = make_float4(0.f, 0.f, 0.f, 0.f);
            if (grow < nrows) v = *(const float4*)&A[(size_t)grow * K + kc + d4 * 4];
            ((float4*)&Alds[0][0])[li] = v;
        }
#pragma unroll
        for (int it = 0; it < 8; ++it) {
            int li = t + it * 256;
            ((float4*)&Wlds[0][0])[li] = ((const float4*)W)[(size_t)kc * 32 + li];
        }
        __syncthreads();
#pragma unroll
        for (int kk = 0; kk < 64; kk += 2) {
            float4 w0 = *(const float4*)&Wlds[kk][tcol * 4];
            float4 w1 = *(const float4*)&Wlds[kk + 1][tcol * 4];
#pragma unroll
            for (int r = 0; r < 8; ++r) {
                float2 a = *(const float2*)&Alds[trow * 8 + r][kk];
                acc[r].x = fmaf(a.x, w0.x, fmaf(a.y, w1.x, acc[r].x));
                acc[r].y = fmaf(a.x, w0.y, fmaf(a.y, w1.y, acc[r].y));
                acc[r].z = fmaf(a.x, w0.z, fmaf(a.y, w1.z, acc[r].z));
                acc[r].w = fmaf(a.x, w0.w, fmaf(a.y, w1.w, acc[r].w));
            }
        }
        __syncthreads();
    }
    if (CHEM_EPI) {
        float4 b4 = ((const float4*)bias)[tcol];
#pragma unroll
        for (int r = 0; r < 8; ++r) {
            int grow = rowBase + trow * 8 + r;
            if (grow < nrows) {
                float m = mask[grow];
                ushort4 pk;
                pk.x = f2bf(fmaxf(acc[r].x + b4.x, 0.f) * m);
                pk.y = f2bf(fmaxf(acc[r].y + b4.y, 0.f) * m);
                pk.z = f2bf(fmaxf(acc[r].z + b4.z, 0.f) * m);
                pk.w = f2bf(fmaxf(acc[r].w + b4.w, 0.f) * m);
                *(ushort4*)&outb[(size_t)grow * HD + tcol * 4] = pk;
            }
        }
    } else {
#pragma unroll
        for (int r = 0; r < 8; ++r) {
            int grow = rowBase + trow * 8 + r;
            if (grow < nrows) ((float4*)out)[(size_t)grow * 32 + tcol] = acc[r];
        }
    }
}

// ---------------- CSR pull aggregation, fused bias+relu+dinv scale ----------------
template <bool BF16OUT>
__global__ __launch_bounds__(256) void gather_kernel(const int* __restrict__ off,
                                                     const int* __restrict__ cnt,
                                                     const int* __restrict__ csr_idx,
                                                     const float* __restrict__ csr_w,
                                                     const float* __restrict__ dinv,
                                                     const float* __restrict__ h,
                                                     const float* __restrict__ bias,
                                                     float* __restrict__ z,
                                                     ushort* __restrict__ zb) {
    int v = blockIdx.x * 4 + (threadIdx.x >> 6);
    if (v >= NN) return;
    int lane = threadIdx.x & 63;
    int s = off[v];
    int e = s + cnt[v];
    float accx = 0.f, accy = 0.f;
    for (; s + 3 < e; s += 4) {
        int r0 = csr_idx[s], r1 = csr_idx[s + 1], r2 = csr_idx[s + 2], r3 = csr_idx[s + 3];
        float w0 = csr_w[s], w1 = csr_w[s + 1], w2 = csr_w[s + 2], w3 = csr_w[s + 3];
        float2 h0 = *(const float2*)&h[(size_t)r0 * HD + lane * 2];
        float2 h1 = *(const float2*)&h[(size_t)r1 * HD + lane * 2];
        float2 h2 = *(const float2*)&h[(size_t)r2 * HD + lane * 2];
        float2 h3 = *(const float2*)&h[(size_t)r3 * HD + lane * 2];
        accx = fmaf(h0.x, w0, accx); accy = fmaf(h0.y, w0, accy);
        accx = fmaf(h1.x, w1, accx); accy = fmaf(h1.y, w1, accy);
        accx = fmaf(h2.x, w2, accx); accy = fmaf(h2.y, w2, accy);
        accx = fmaf(h3.x, w3, accx); accy = fmaf(h3.y, w3, accy);
    }
    for (; s < e; ++s) {
        int r0 = csr_idx[s];
        float w0 = csr_w[s];
        float2 h0 = *(const float2*)&h[(size_t)r0 * HD + lane * 2];
        accx = fmaf(h0.x, w0, accx); accy = fmaf(h0.y, w0, accy);
    }
    float dv = dinv[v];
    float2 b = *(const float2*)&bias[lane * 2];
    float ox = fmaxf(fmaf(accx, dv, b.x), 0.f);
    float oy = fmaxf(fmaf(accy, dv, b.y), 0.f);
    if (BF16OUT) {
        unsigned pk = (unsigned)f2bf(ox) | ((unsigned)f2bf(oy) << 16);
        *(unsigned*)&zb[(size_t)v * HD + lane * 2] = pk;
    } else {
        float2 o; o.x = ox; o.y = oy;
        *(float2*)&z[(size_t)v * HD + lane * 2] = o;
    }
}

// ---------------- decoder: bf16 MFMA, fused pos+neg ----------------
// block: 64 edges, 4 waves; wave = M-tile of 16 edges. F[64][256] bf16 staged
// frag-major in LDS; W1 fragments streamed from global (L2-resident).
__global__ __launch_bounds__(256) void decode_mfma_kernel(const int* __restrict__ pos_edge,
                                                          const int* __restrict__ neg_edge,
                                                          const ushort* __restrict__ zb,
                                                          const ushort* __restrict__ cb,
                                                          const ushort* __restrict__ w1f,
                                                          const float* __restrict__ b1,
                                                          const float* __restrict__ w2,
                                                          const float* __restrict__ b2,
                                                          float* __restrict__ out) {
    __shared__ ushort Flds[8 * 4 * 64 * 8];  // [ks][mt][lane][j] = 32 KB
    __shared__ int sEdge[128];
    const int t = threadIdx.x;
    const int wave = t >> 6, lane = t & 63;
    const int bid = blockIdx.x;
    const bool isPos = bid < (NEP / 64);
    const int* edges = isPos ? pos_edge : neg_edge;
    const int ebase = (isPos ? bid : bid - NEP / 64) * 64;
    float* op = out + (isPos ? 0 : NEP);

    if (t < 128) sEdge[t] = edges[(size_t)ebase * 2 + t];
    __syncthreads();

    // stage F = [z_s*z_d | c_s*c_d] as bf16, frag-major (conflict-free lane*16B)
#pragma unroll
    for (int it = 0; it < 8; ++it) {
        int ch = t + it * 256;       // [0,2048)
        int e = ch & 63, d8 = ch >> 6;  // edge, dim-octet (8 elems)
        int s = sEdge[e * 2], dd = sEdge[e * 2 + 1];
        const ushort* src = (d8 < 16) ? zb : cb;
        int doff = (d8 & 15) << 3;
        uint4 av = *(const uint4*)&src[(size_t)s * HD + doff];
        uint4 bv = *(const uint4*)&src[(size_t)dd * HD + doff];
        const ushort* ap = (const ushort*)&av;
        const ushort* bp = (const ushort*)&bv;
        ushort res[8];
#pragma unroll
        for (int j = 0; j < 8; ++j) res[j] = f2bf(bf2f(ap[j]) * bf2f(bp[j]));
        int ks = d8 >> 2;
        int mt = e >> 4;
        int fl = (e & 15) | ((d8 & 3) << 4);
        ((uint4*)Flds)[(ks * 4 + mt) * 64 + fl] = *(uint4*)res;
    }
    __syncthreads();

    f32x4 acc[8] = {};
    const int mt = wave;
#pragma unroll
    for (int ks = 0; ks < 8; ++ks) {
        bf16x8 afrag = ((const bf16x8*)Flds)[(ks * 4 + mt) * 64 + lane];
#pragma unroll
        for (int nt = 0; nt < 8; ++nt) {
            bf16x8 bfrag = ((const bf16x8*)w1f)[(size_t)(ks * 8 + nt) * 64 + lane];
            acc[nt] = __builtin_amdgcn_mfma_f32_16x16x32_bf16(afrag, bfrag, acc[nt], 0, 0, 0);
        }
    }

    // epilogue: hmid = relu(S + b1); out = hmid @ W2 + b2
    // D layout: col = lane&15, row = (lane>>4)*4 + reg
    const int c0 = lane & 15;
    float p[4] = {0.f, 0.f, 0.f, 0.f};
#pragma unroll
    for (int nt = 0; nt < 8; ++nt) {
        float b1v = b1[nt * 16 + c0];
        float w2v = w2[nt * 16 + c0];
#pragma unroll
        for (int reg = 0; reg < 4; ++reg) {
            float h = fmaxf(acc[nt][reg] + b1v, 0.f);
            p[reg] = fmaf(h, w2v, p[reg]);
        }
    }
    float b2v = b2[0];
#pragma unroll
    for (int reg = 0; reg < 4; ++reg) {
        float v = p[reg];
        v += __shfl_xor(v, 1);
        v += __shfl_xor(v, 2);
        v += __shfl_xor(v, 4);
        v += __shfl_xor(v, 8);
        if (c0 == 0) op[ebase + mt * 16 + (lane >> 4) * 4 + reg] = v + b2v;
    }
}

extern "C" void kernel_launch(void* const* d_in, const int* in_sizes, int n_in,
                              void* d_out, int out_size, void* d_ws, size_t ws_size,
                              hipStream_t stream) {
    const int* edge_index = (const int*)d_in[0];
    const float* chemistry = (const float*)d_in[1];
    const int* pos_edge = (const int*)d_in[2];
    const int* neg_edge = (const int*)d_in[3];
    const float* smiles_mask = (const float*)d_in[4];
    const float* node_emb = (const float*)d_in[5];
    const float* conv_w = (const float*)d_in[6];
    const float* conv_b = (const float*)d_in[7];
    const float* chem_w = (const float*)d_in[8];
    const float* chem_b = (const float*)d_in[9];
    const float* dec_w1 = (const float*)d_in[10];
    const float* dec_b1 = (const float*)d_in[11];
    const float* dec_w2 = (const float*)d_in[12];
    const float* dec_b2 = (const float*)d_in[13];
    float* out = (float*)d_out;

    char* ws = (char*)d_ws;
    int* cnt = (int*)(ws + 0);
    float* dinv = (float*)(ws + 204800);
    int* partial = (int*)(ws + 409600);
    int* off = (int*)(ws + 614400);
    int* cursor = (int*)(ws + 819200);
    int* bsum = (int*)(ws + 1024000);
    int* csr_idx = (int*)(ws + 1048576);    // 4 MB
    float* csr_w = (float*)(ws + 5242880);  // 4 MB
    float* bufZ = (float*)(ws + 9437184);   // 25.6 MB
    float* bufH = (float*)(ws + 35037184);  // 25.6 MB
    ushort* zb = (ushort*)(ws + 60637184);  // 12.8 MB
    ushort* cb = (ushort*)(ws + 73437184);  // 12.8 MB
    ushort* w1f = (ushort*)(ws + 86237184); // 64 KB

    const int* e_row = edge_index;
    const int* e_col = edge_index + NE;

    // ---- CSR build + W1 fragment pack ----
    hipMemsetAsync(cnt, 0, (size_t)NN * 4, stream);
    count_kernel<<<(NE + 255) / 256, 256, 0, stream>>>(e_col, cnt);
    dinv_kernel<<<(NN + 255) / 256, 256, 0, stream>>>(cnt, dinv);
    scan1_kernel<<<NB_SCAN, 256, 0, stream>>>(cnt, partial, bsum);
    scan2_kernel<<<1, 256, 0, stream>>>(bsum);
    scan3_kernel<<<NB_SCAN, 256, 0, stream>>>(partial, bsum, off, cursor);
    fill_kernel<<<(NE + 255) / 256, 256, 0, stream>>>(e_row, e_col, dinv, cursor, csr_idx, csr_w);
    w1frag_kernel<<<16, 256, 0, stream>>>(dec_w1, w1f);

    const int mmGrid = (NN + 63) / 64;
    const int gaGrid = (NN + 3) / 4;

    // layer 0
    matmul_kernel<HD, false><<<mmGrid, 256, 0, stream>>>(node_emb, conv_w, nullptr, nullptr, bufH, nullptr, NN);
    gather_kernel<false><<<gaGrid, 256, 0, stream>>>(off, cnt, csr_idx, csr_w, dinv, bufH, conv_b, bufZ, nullptr);

    // layer 1 (z emitted in bf16 for decode)
    matmul_kernel<HD, false><<<mmGrid, 256, 0, stream>>>(bufZ, conv_w + HD * HD, nullptr, nullptr, bufH, nullptr, NN);
    gather_kernel<true><<<gaGrid, 256, 0, stream>>>(off, cnt, csr_idx, csr_w, dinv, bufH, conv_b + HD, nullptr, zb);

    // chemistry features (bf16 out)
    matmul_kernel<CD, true><<<mmGrid, 256, 0, stream>>>(chemistry, chem_w, chem_b, smiles_mask, nullptr, cb, NN);

    // decode pos+neg fused
    decode_mfma_kernel<<<2 * (NEP / 64), 256, 0, stream>>>(pos_edge, neg_edge, zb, cb, w1f,
                                                           dec_b1, dec_w2, dec_b2, out);
}

// Round 4
// 482.891 us; speedup vs baseline: 5.6013x; 1.5367x over previous
//
#include <hip/hip_runtime.h>
#include <hip/hip_bf16.h>

#define NN 50000
#define NE 1000000
#define NEP 400000
#define HD 128
#define CD 768
#define NB_SCAN 196  // ceil(NN/256)
#define CKS 24       // 768/32

typedef __attribute__((ext_vector_type(8))) short bf16x8;
typedef __attribute__((ext_vector_type(4))) float f32x4;

__device__ __forceinline__ ushort f2bf(float x) {
    unsigned u = __float_as_uint(x);
    u += 0x7FFF + ((u >> 16) & 1);  // RNE
    return (ushort)(u >> 16);
}
__device__ __forceinline__ float bf2f(ushort b) {
    return __uint_as_float(((unsigned)b) << 16);
}
__device__ __forceinline__ unsigned pk2bf(float a, float b) {
    __hip_bfloat162 h = __float22bfloat162_rn(make_float2(a, b));
    return *(unsigned*)&h;
}
__device__ __forceinline__ bf16x8 pack8(float4 a0, float4 a1) {
    union { unsigned u[4]; bf16x8 v; } r;
    r.u[0] = pk2bf(a0.x, a0.y);
    r.u[1] = pk2bf(a0.z, a0.w);
    r.u[2] = pk2bf(a1.x, a1.y);
    r.u[3] = pk2bf(a1.z, a1.w);
    return r.v;
}

// ---------------- CSR build ----------------
__global__ __launch_bounds__(256) void count_kernel(const int* __restrict__ col,
                                                    int* __restrict__ cnt) {
    int i = blockIdx.x * 256 + threadIdx.x;
    if (i < NE) atomicAdd(&cnt[col[i]], 1);
}

__global__ __launch_bounds__(256) void dinv_kernel(const int* __restrict__ cnt,
                                                   float* __restrict__ dinv) {
    int i = blockIdx.x * 256 + threadIdx.x;
    if (i < NN) {
        int d = cnt[i];
        dinv[i] = (d > 0) ? 1.0f / sqrtf((float)d) : 0.0f;
    }
}

__global__ __launch_bounds__(256) void scan1_kernel(const int* __restrict__ cnt,
                                                    int* __restrict__ partial,
                                                    int* __restrict__ bsum) {
    __shared__ int s[256];
    int i = blockIdx.x * 256 + threadIdx.x;
    int v = (i < NN) ? cnt[i] : 0;
    s[threadIdx.x] = v;
    __syncthreads();
    for (int o = 1; o < 256; o <<= 1) {
        int t = (threadIdx.x >= o) ? s[threadIdx.x - o] : 0;
        __syncthreads();
        s[threadIdx.x] += t;
        __syncthreads();
    }
    if (i < NN) partial[i] = s[threadIdx.x] - v;
    if (threadIdx.x == 255) bsum[blockIdx.x] = s[255];
}

__global__ __launch_bounds__(256) void scan2_kernel(int* __restrict__ bsum) {
    __shared__ int s[256];
    int v = (threadIdx.x < NB_SCAN) ? bsum[threadIdx.x] : 0;
    s[threadIdx.x] = v;
    __syncthreads();
    for (int o = 1; o < 256; o <<= 1) {
        int t = (threadIdx.x >= o) ? s[threadIdx.x - o] : 0;
        __syncthreads();
        s[threadIdx.x] += t;
        __syncthreads();
    }
    if (threadIdx.x < NB_SCAN) bsum[threadIdx.x] = s[threadIdx.x] - v;
}

__global__ __launch_bounds__(256) void scan3_kernel(const int* __restrict__ partial,
                                                    const int* __restrict__ bsum,
                                                    int* __restrict__ off,
                                                    int* __restrict__ cursor) {
    int i = blockIdx.x * 256 + threadIdx.x;
    if (i < NN) {
        int o = partial[i] + bsum[blockIdx.x];
        off[i] = o;
        cursor[i] = o;
    }
}

__global__ __launch_bounds__(256) void fill_kernel(const int* __restrict__ row,
                                                   const int* __restrict__ col,
                                                   const float* __restrict__ dinv,
                                                   int* __restrict__ cursor,
                                                   int* __restrict__ csr_idx,
                                                   float* __restrict__ csr_w) {
    int e = blockIdx.x * 256 + threadIdx.x;
    if (e < NE) {
        int c = col[e], r = row[e];
        int slot = atomicAdd(&cursor[c], 1);
        csr_idx[slot] = r;
        csr_w[slot] = dinv[r];
    }
}

// ---------------- W(K x 128) -> MFMA B-fragment order, bf16 ----------------
// wf[((ks*8+nt)*64 + l)*8 + j] = W[ks*32 + (l>>4)*8 + j][nt*16 + (l&15)]
// launch with grid = nks*8*64/256 blocks
__global__ __launch_bounds__(256) void wfrag_kernel(const float* __restrict__ w,
                                                    ushort* __restrict__ wf) {
    int tid = blockIdx.x * 256 + threadIdx.x;
    int ks = tid >> 9, nt = (tid >> 6) & 7, l = tid & 63;
    int kbase = ks * 32 + ((l >> 4) << 3);
    int colq = nt * 16 + (l & 15);
    ushort r[8];
#pragma unroll
    for (int j = 0; j < 8; ++j) r[j] = f2bf(w[(size_t)(kbase + j) * HD + colq]);
    *(uint4*)&wf[(size_t)tid * 8] = *(uint4*)r;
}

// ---------------- conv matmul: h(nrows x 128) = A(nrows x 128) @ W(128 x 128), bf16 out ----------------
__global__ __launch_bounds__(256) void matmul_kernel(const float* __restrict__ A,
                                                     const float* __restrict__ W,
                                                     ushort* __restrict__ outb,
                                                     int nrows) {
    __shared__ float Alds[64][64];
    __shared__ float Wlds[64][128];
    const int t = threadIdx.x;
    const int tcol = t & 31, trow = t >> 5;
    const int rowBase = blockIdx.x * 64;

    float4 acc[8];
#pragma unroll
    for (int r = 0; r < 8; ++r) acc[r] = make_float4(0.f, 0.f, 0.f, 0.f);

    for (int kc = 0; kc < HD; kc += 64) {
#pragma unroll
        for (int it = 0; it < 4; ++it) {
            int li = t + it * 256;
            int r = li >> 4, d4 = li & 15;
            int grow = rowBase + r;
            float4 v = make_float4(0.f, 0.f, 0.f, 0.f);
            if (grow < nrows) v = *(const float4*)&A[(size_t)grow * HD + kc + d4 * 4];
            ((float4*)&Alds[0][0])[li] = v;
        }
#pragma unroll
        for (int it = 0; it < 8; ++it) {
            int li = t + it * 256;
            ((float4*)&Wlds[0][0])[li] = ((const float4*)W)[(size_t)kc * 32 + li];
        }
        __syncthreads();
#pragma unroll
        for (int kk = 0; kk < 64; kk += 2) {
            float4 w0 = *(const float4*)&Wlds[kk][tcol * 4];
            float4 w1 = *(const float4*)&Wlds[kk + 1][tcol * 4];
#pragma unroll
            for (int r = 0; r < 8; ++r) {
                float2 a = *(const float2*)&Alds[trow * 8 + r][kk];
                acc[r].x = fmaf(a.x, w0.x, fmaf(a.y, w1.x, acc[r].x));
                acc[r].y = fmaf(a.x, w0.y, fmaf(a.y, w1.y, acc[r].y));
                acc[r].z = fmaf(a.x, w0.z, fmaf(a.y, w1.z, acc[r].z));
                acc[r].w = fmaf(a.x, w0.w, fmaf(a.y, w1.w, acc[r].w));
            }
        }
        __syncthreads();
    }
#pragma unroll
    for (int r = 0; r < 8; ++r) {
        int grow = rowBase + trow * 8 + r;
        if (grow < nrows) {
            uint2 pk;
            pk.x = pk2bf(acc[r].x, acc[r].y);
            pk.y = pk2bf(acc[r].z, acc[r].w);
            *(uint2*)&outb[(size_t)grow * HD + tcol * 4] = pk;
        }
    }
}

// ---------------- chem: cb(NN x 128) = bf16mfma(chemistry(NN x 768) @ chem_w) + bias, relu, mask ----------------
__global__ __launch_bounds__(256) void chem_mfma_kernel(const float* __restrict__ chem,
                                                        const ushort* __restrict__ wcf,
                                                        const float* __restrict__ bias,
                                                        const float* __restrict__ mask,
                                                        ushort* __restrict__ cb) {
    __shared__ float At[64][40];  // padded: bank stride 8 -> 4-way on frag read, ok
    const int t = threadIdx.x;
    const int w = t >> 6, lane = t & 63;
    const int rowBase = blockIdx.x * 64;
    const int nt0 = w * 2;

    f32x4 acc[4][2] = {};

    for (int ks = 0; ks < CKS; ++ks) {
        __syncthreads();
#pragma unroll
        for (int i = 0; i < 2; ++i) {
            int li = t + i * 256;           // [0,512) float4 tasks
            int r = li >> 3, c4 = li & 7;   // row, float4-col
            int grow = rowBase + r;
            float4 v = make_float4(0.f, 0.f, 0.f, 0.f);
            if (grow < NN) v = *(const float4*)&chem[(size_t)grow * CD + ks * 32 + c4 * 4];
            *(float4*)&At[r][c4 * 4] = v;
        }
        __syncthreads();
        bf16x8 bf0 = ((const bf16x8*)wcf)[(ks * 8 + nt0) * 64 + lane];
        bf16x8 bf1 = ((const bf16x8*)wcf)[(ks * 8 + nt0 + 1) * 64 + lane];
#pragma unroll
        for (int mt = 0; mt < 4; ++mt) {
            int row = mt * 16 + (lane & 15);
            float4 a0 = *(const float4*)&At[row][(lane >> 4) * 8];
            float4 a1 = *(const float4*)&At[row][(lane >> 4) * 8 + 4];
            bf16x8 af = pack8(a0, a1);
            acc[mt][0] = __builtin_amdgcn_mfma_f32_16x16x32_bf16(af, bf0, acc[mt][0], 0, 0, 0);
            acc[mt][1] = __builtin_amdgcn_mfma_f32_16x16x32_bf16(af, bf1, acc[mt][1], 0, 0, 0);
        }
    }

    const int c0 = lane & 15, rq = lane >> 4;
    float bb0 = bias[nt0 * 16 + c0];
    float bb1 = bias[nt0 * 16 + 16 + c0];
#pragma unroll
    for (int mt = 0; mt < 4; ++mt) {
#pragma unroll
        for (int reg = 0; reg < 4; ++reg) {
            int grow = rowBase + mt * 16 + rq * 4 + reg;
            if (grow < NN) {
                float m = mask[grow];
                cb[(size_t)grow * HD + nt0 * 16 + c0] = f2bf(fmaxf(acc[mt][0][reg] + bb0, 0.f) * m);
                cb[(size_t)grow * HD + nt0 * 16 + 16 + c0] = f2bf(fmaxf(acc[mt][1][reg] + bb1, 0.f) * m);
            }
        }
    }
}

// ---------------- CSR pull aggregation (bf16 h), fused bias+relu+dinv scale ----------------
template <bool BF16OUT>
__global__ __launch_bounds__(256) void gather_kernel(const int* __restrict__ off,
                                                     const int* __restrict__ cnt,
                                                     const int* __restrict__ csr_idx,
                                                     const float* __restrict__ csr_w,
                                                     const float* __restrict__ dinv,
                                                     const ushort* __restrict__ h,
                                                     const float* __restrict__ bias,
                                                     float* __restrict__ z,
                                                     ushort* __restrict__ zb) {
    int v = blockIdx.x * 4 + (threadIdx.x >> 6);
    if (v >= NN) return;
    int lane = threadIdx.x & 63;
    int s = off[v];
    int e = s + cnt[v];
    float accx = 0.f, accy = 0.f;
    for (; s + 3 < e; s += 4) {
        int r0 = csr_idx[s], r1 = csr_idx[s + 1], r2 = csr_idx[s + 2], r3 = csr_idx[s + 3];
        float w0 = csr_w[s], w1 = csr_w[s + 1], w2 = csr_w[s + 2], w3 = csr_w[s + 3];
        unsigned u0 = *(const unsigned*)&h[(size_t)r0 * HD + lane * 2];
        unsigned u1 = *(const unsigned*)&h[(size_t)r1 * HD + lane * 2];
        unsigned u2 = *(const unsigned*)&h[(size_t)r2 * HD + lane * 2];
        unsigned u3 = *(const unsigned*)&h[(size_t)r3 * HD + lane * 2];
        accx = fmaf(bf2f((ushort)u0), w0, accx); accy = fmaf(bf2f((ushort)(u0 >> 16)), w0, accy);
        accx = fmaf(bf2f((ushort)u1), w1, accx); accy = fmaf(bf2f((ushort)(u1 >> 16)), w1, accy);
        accx = fmaf(bf2f((ushort)u2), w2, accx); accy = fmaf(bf2f((ushort)(u2 >> 16)), w2, accy);
        accx = fmaf(bf2f((ushort)u3), w3, accx); accy = fmaf(bf2f((ushort)(u3 >> 16)), w3, accy);
    }
    for (; s < e; ++s) {
        int r0 = csr_idx[s];
        float w0 = csr_w[s];
        unsigned u0 = *(const unsigned*)&h[(size_t)r0 * HD + lane * 2];
        accx = fmaf(bf2f((ushort)u0), w0, accx); accy = fmaf(bf2f((ushort)(u0 >> 16)), w0, accy);
    }
    float dv = dinv[v];
    float2 b = *(const float2*)&bias[lane * 2];
    float ox = fmaxf(fmaf(accx, dv, b.x), 0.f);
    float oy = fmaxf(fmaf(accy, dv, b.y), 0.f);
    if (BF16OUT) {
        *(unsigned*)&zb[(size_t)v * HD + lane * 2] = pk2bf(ox, oy);
    } else {
        float2 o; o.x = ox; o.y = oy;
        *(float2*)&z[(size_t)v * HD + lane * 2] = o;
    }
}

// ---------------- decoder: bf16 MFMA, fused pos+neg ----------------
// block = 64 edges, 4 waves; wave covers all 4 mt x its 2 nt.
// Staging: 16 consecutive lanes read 16 consecutive 16B segments (coalesced).
__global__ __launch_bounds__(256) void decode_mfma_kernel(const int* __restrict__ pos_edge,
                                                          const int* __restrict__ neg_edge,
                                                          const ushort* __restrict__ zb,
                                                          const ushort* __restrict__ cb,
                                                          const ushort* __restrict__ w1f,
                                                          const float* __restrict__ b1,
                                                          const float* __restrict__ w2,
                                                          const float* __restrict__ b2,
                                                          float* __restrict__ out) {
    __shared__ ushort Flds[8 * 4 * 64 * 8];  // 32 KB, uint4-indexed, xor-swizzled
    __shared__ int sEdge[128];
    __shared__ float part[4][64];
    const int t = threadIdx.x;
    const int w = t >> 6, lane = t & 63;
    const int bid = blockIdx.x;
    const bool isPos = bid < (NEP / 64);
    const int* edges = isPos ? pos_edge : neg_edge;
    const int ebase = (isPos ? bid : bid - NEP / 64) * 64;
    float* op = out + (isPos ? 0 : NEP);

    if (t < 128) sEdge[t] = edges[(size_t)ebase * 2 + t];
    __syncthreads();

    const int seg = lane & 15, esub = lane >> 4;
#pragma unroll
    for (int it = 0; it < 8; ++it) {
        int e = ((it & 3) << 4) | (w << 2) | esub;
        int half = it >> 2;
        const ushort* src = half ? cb : zb;
        int s = sEdge[2 * e], dd = sEdge[2 * e + 1];
        uint4 av = *(const uint4*)&src[(size_t)s * HD + seg * 8];
        uint4 bv = *(const uint4*)&src[(size_t)dd * HD + seg * 8];
        const ushort* ap = (const ushort*)&av;
        const ushort* bp = (const ushort*)&bv;
        uint4 res;
        res.x = pk2bf(bf2f(ap[0]) * bf2f(bp[0]), bf2f(ap[1]) * bf2f(bp[1]));
        res.y = pk2bf(bf2f(ap[2]) * bf2f(bp[2]), bf2f(ap[3]) * bf2f(bp[3]));
        res.z = pk2bf(bf2f(ap[4]) * bf2f(bp[4]), bf2f(ap[5]) * bf2f(bp[5]));
        res.w = pk2bf(bf2f(ap[6]) * bf2f(bp[6]), bf2f(ap[7]) * bf2f(bp[7]));
        int ks = half * 4 + (seg >> 2);
        int mt = it & 3;
        int fl = (e & 15) | ((seg & 3) << 4);
        int idx = (((ks * 4 + mt) * 64) + fl) ^ ((ks & 1) << 2);
        ((uint4*)Flds)[idx] = res;
    }
    __syncthreads();

    f32x4 acc[4][2] = {};
    const int nt0 = w * 2;
#pragma unroll
    for (int ks = 0; ks < 8; ++ks) {
        bf16x8 bf0 = ((const bf16x8*)w1f)[(ks * 8 + nt0) * 64 + lane];
        bf16x8 bf1 = ((const bf16x8*)w1f)[(ks * 8 + nt0 + 1) * 64 + lane];
#pragma unroll
        for (int mt = 0; mt < 4; ++mt) {
            bf16x8 af = ((const bf16x8*)Flds)[((ks * 4 + mt) * 64) + (lane ^ ((ks & 1) << 2))];
            acc[mt][0] = __builtin_amdgcn_mfma_f32_16x16x32_bf16(af, bf0, acc[mt][0], 0, 0, 0);
            acc[mt][1] = __builtin_amdgcn_mfma_f32_16x16x32_bf16(af, bf1, acc[mt][1], 0, 0, 0);
        }
    }

    // epilogue: hmid = relu(S + b1); partial = hmid @ w2 over this wave's 32 cols
    const int c0 = lane & 15, rq = lane >> 4;
    float b1v0 = b1[nt0 * 16 + c0], b1v1 = b1[nt0 * 16 + 16 + c0];
    float w2v0 = w2[nt0 * 16 + c0], w2v1 = w2[nt0 * 16 + 16 + c0];
#pragma unroll
    for (int mt = 0; mt < 4; ++mt) {
#pragma unroll
        for (int reg = 0; reg < 4; ++reg) {
            float h0 = fmaxf(acc[mt][0][reg] + b1v0, 0.f);
            float h1 = fmaxf(acc[mt][1][reg] + b1v1, 0.f);
            float p = fmaf(h0, w2v0, h1 * w2v1);
            p += __shfl_xor(p, 1);
            p += __shfl_xor(p, 2);
            p += __shfl_xor(p, 4);
            p += __shfl_xor(p, 8);
            if (c0 == 0) part[w][mt * 16 + rq * 4 + reg] = p;
        }
    }
    __syncthreads();
    if (t < 64) {
        op[ebase + t] = part[0][t] + part[1][t] + part[2][t] + part[3][t] + b2[0];
    }
}

extern "C" void kernel_launch(void* const* d_in, const int* in_sizes, int n_in,
                              void* d_out, int out_size, void* d_ws, size_t ws_size,
                              hipStream_t stream) {
    const int* edge_index = (const int*)d_in[0];
    const float* chemistry = (const float*)d_in[1];
    const int* pos_edge = (const int*)d_in[2];
    const int* neg_edge = (const int*)d_in[3];
    const float* smiles_mask = (const float*)d_in[4];
    const float* node_emb = (const float*)d_in[5];
    const float* conv_w = (const float*)d_in[6];
    const float* conv_b = (const float*)d_in[7];
    const float* chem_w = (const float*)d_in[8];
    const float* chem_b = (const float*)d_in[9];
    const float* dec_w1 = (const float*)d_in[10];
    const float* dec_b1 = (const float*)d_in[11];
    const float* dec_w2 = (const float*)d_in[12];
    const float* dec_b2 = (const float*)d_in[13];
    float* out = (float*)d_out;

    char* ws = (char*)d_ws;
    int* cnt = (int*)(ws + 0);
    float* dinv = (float*)(ws + 204800);
    int* partial = (int*)(ws + 409600);
    int* off = (int*)(ws + 614400);
    int* cursor = (int*)(ws + 819200);
    int* bsum = (int*)(ws + 1024000);
    int* csr_idx = (int*)(ws + 1048576);     // 4 MB
    float* csr_w = (float*)(ws + 5242880);   // 4 MB
    float* bufZ = (float*)(ws + 9437184);    // 25.6 MB
    ushort* hb = (ushort*)(ws + 35037184);   // 12.8 MB
    ushort* zb = (ushort*)(ws + 47837184);   // 12.8 MB
    ushort* cb = (ushort*)(ws + 60637184);   // 12.8 MB
    ushort* w1f = (ushort*)(ws + 73437184);  // 64 KB
    ushort* wcf = (ushort*)(ws + 73502720);  // 192 KB

    const int* e_row = edge_index;
    const int* e_col = edge_index + NE;

    // ---- CSR build + weight fragment packs ----
    hipMemsetAsync(cnt, 0, (size_t)NN * 4, stream);
    count_kernel<<<(NE + 255) / 256, 256, 0, stream>>>(e_col, cnt);
    dinv_kernel<<<(NN + 255) / 256, 256, 0, stream>>>(cnt, dinv);
    scan1_kernel<<<NB_SCAN, 256, 0, stream>>>(cnt, partial, bsum);
    scan2_kernel<<<1, 256, 0, stream>>>(bsum);
    scan3_kernel<<<NB_SCAN, 256, 0, stream>>>(partial, bsum, off, cursor);
    fill_kernel<<<(NE + 255) / 256, 256, 0, stream>>>(e_row, e_col, dinv, cursor, csr_idx, csr_w);
    wfrag_kernel<<<16, 256, 0, stream>>>(dec_w1, w1f);   // 8 ks
    wfrag_kernel<<<48, 256, 0, stream>>>(chem_w, wcf);   // 24 ks

    const int mmGrid = (NN + 63) / 64;
    const int gaGrid = (NN + 3) / 4;

    // layer 0
    matmul_kernel<<<mmGrid, 256, 0, stream>>>(node_emb, conv_w, hb, NN);
    gather_kernel<false><<<gaGrid, 256, 0, stream>>>(off, cnt, csr_idx, csr_w, dinv, hb, conv_b, bufZ, nullptr);

    // layer 1 (z emitted in bf16 for decode)
    matmul_kernel<<<mmGrid, 256, 0, stream>>>(bufZ, conv_w + HD * HD, hb, NN);
    gather_kernel<true><<<gaGrid, 256, 0, stream>>>(off, cnt, csr_idx, csr_w, dinv, hb, conv_b + HD, nullptr, zb);

    // chemistry features via MFMA (bf16 out)
    chem_mfma_kernel<<<mmGrid, 256, 0, stream>>>(chemistry, wcf, chem_b, smiles_mask, cb);

    // decode pos+neg fused
    decode_mfma_kernel<<<2 * (NEP / 64), 256, 0, stream>>>(pos_edge, neg_edge, zb, cb, w1f,
                                                           dec_b1, dec_w2, dec_b2, out);
}

// Round 5
// 460.515 us; speedup vs baseline: 5.8735x; 1.0486x over previous
//
#include <hip/hip_runtime.h>
#include <hip/hip_bf16.h>

#define NN 50000
#define NE 1000000
#define NEP 400000
#define HD 128
#define CD 768
#define NB_SCAN 196  // ceil(NN/256)
#define FSTR 256     // feat row stride (ushorts): [z(128) | c(128)]

typedef __attribute__((ext_vector_type(8))) short bf16x8;
typedef __attribute__((ext_vector_type(4))) float f32x4;

__device__ __forceinline__ ushort f2bf(float x) {
    unsigned u = __float_as_uint(x);
    u += 0x7FFF + ((u >> 16) & 1);  // RNE
    return (ushort)(u >> 16);
}
__device__ __forceinline__ float bf2f(ushort b) {
    return __uint_as_float(((unsigned)b) << 16);
}
__device__ __forceinline__ unsigned pk2bf(float a, float b) {
    __hip_bfloat162 h = __float22bfloat162_rn(make_float2(a, b));
    return *(unsigned*)&h;
}
__device__ __forceinline__ bf16x8 pack8(float4 a0, float4 a1) {
    union { unsigned u[4]; bf16x8 v; } r;
    r.u[0] = pk2bf(a0.x, a0.y);
    r.u[1] = pk2bf(a0.z, a0.w);
    r.u[2] = pk2bf(a1.x, a1.y);
    r.u[3] = pk2bf(a1.z, a1.w);
    return r.v;
}

// ---------------- CSR build ----------------
__global__ __launch_bounds__(256) void count_kernel(const int* __restrict__ col,
                                                    int* __restrict__ cnt) {
    int i = blockIdx.x * 256 + threadIdx.x;
    if (i < NE) atomicAdd(&cnt[col[i]], 1);
}

__global__ __launch_bounds__(256) void dinv_kernel(const int* __restrict__ cnt,
                                                   float* __restrict__ dinv) {
    int i = blockIdx.x * 256 + threadIdx.x;
    if (i < NN) {
        int d = cnt[i];
        dinv[i] = (d > 0) ? 1.0f / sqrtf((float)d) : 0.0f;
    }
}

__global__ __launch_bounds__(256) void scan1_kernel(const int* __restrict__ cnt,
                                                    int* __restrict__ partial,
                                                    int* __restrict__ bsum) {
    __shared__ int s[256];
    int i = blockIdx.x * 256 + threadIdx.x;
    int v = (i < NN) ? cnt[i] : 0;
    s[threadIdx.x] = v;
    __syncthreads();
    for (int o = 1; o < 256; o <<= 1) {
        int t = (threadIdx.x >= o) ? s[threadIdx.x - o] : 0;
        __syncthreads();
        s[threadIdx.x] += t;
        __syncthreads();
    }
    if (i < NN) partial[i] = s[threadIdx.x] - v;
    if (threadIdx.x == 255) bsum[blockIdx.x] = s[255];
}

__global__ __launch_bounds__(256) void scan2_kernel(int* __restrict__ bsum) {
    __shared__ int s[256];
    int v = (threadIdx.x < NB_SCAN) ? bsum[threadIdx.x] : 0;
    s[threadIdx.x] = v;
    __syncthreads();
    for (int o = 1; o < 256; o <<= 1) {
        int t = (threadIdx.x >= o) ? s[threadIdx.x - o] : 0;
        __syncthreads();
        s[threadIdx.x] += t;
        __syncthreads();
    }
    if (threadIdx.x < NB_SCAN) bsum[threadIdx.x] = s[threadIdx.x] - v;
}

__global__ __launch_bounds__(256) void scan3_kernel(const int* __restrict__ partial,
                                                    const int* __restrict__ bsum,
                                                    int* __restrict__ off,
                                                    int* __restrict__ cursor) {
    int i = blockIdx.x * 256 + threadIdx.x;
    if (i < NN) {
        int o = partial[i] + bsum[blockIdx.x];
        off[i] = o;
        cursor[i] = o;
    }
}

__global__ __launch_bounds__(256) void fill_kernel(const int* __restrict__ row,
                                                   const int* __restrict__ col,
                                                   const float* __restrict__ dinv,
                                                   int* __restrict__ cursor,
                                                   int* __restrict__ csr_idx,
                                                   float* __restrict__ csr_w) {
    int e = blockIdx.x * 256 + threadIdx.x;
    if (e < NE) {
        int c = col[e], r = row[e];
        int slot = atomicAdd(&cursor[c], 1);
        csr_idx[slot] = r;
        csr_w[slot] = dinv[r];
    }
}

// ---------------- W(K x 128) -> MFMA B-fragment order, bf16 ----------------
// wf[((ks*8+nt)*64 + l)*8 + j] = W[ks*32 + (l>>4)*8 + j][nt*16 + (l&15)]
__global__ __launch_bounds__(256) void wfrag_kernel(const float* __restrict__ w,
                                                    ushort* __restrict__ wf) {
    int tid = blockIdx.x * 256 + threadIdx.x;
    int ks = tid >> 9, nt = (tid >> 6) & 7, l = tid & 63;
    int kbase = ks * 32 + ((l >> 4) << 3);
    int colq = nt * 16 + (l & 15);
    ushort r[8];
#pragma unroll
    for (int j = 0; j < 8; ++j) r[j] = f2bf(w[(size_t)(kbase + j) * HD + colq]);
    *(uint4*)&wf[(size_t)tid * 8] = *(uint4*)r;
}

// ---------------- MFMA matmul: out(NN x 128) = bf16(A(NN x KS*32)) @ Wfrag, optional chem epilogue ----------------
template <int KS, bool EPI>
__global__ __launch_bounds__(256) void feat_mfma_kernel(const float* __restrict__ A,
                                                        const ushort* __restrict__ wf,
                                                        const float* __restrict__ bias,
                                                        const float* __restrict__ mask,
                                                        ushort* __restrict__ out,
                                                        int ostride, int ooff) {
    __shared__ float At[64][36];
    const int t = threadIdx.x;
    const int w = t >> 6, lane = t & 63;
    const int rowBase = blockIdx.x * 64;
    const int nt0 = w * 2;
    const int K = KS * 32;

    f32x4 acc[4][2] = {};

    for (int ks = 0; ks < KS; ++ks) {
        __syncthreads();
#pragma unroll
        for (int i = 0; i < 2; ++i) {
            int li = t + i * 256;           // [0,512) float4 tasks
            int r = li >> 3, c4 = li & 7;   // row, float4-col
            int grow = rowBase + r;
            float4 v = make_float4(0.f, 0.f, 0.f, 0.f);
            if (grow < NN) v = *(const float4*)&A[(size_t)grow * K + ks * 32 + c4 * 4];
            *(float4*)&At[r][c4 * 4] = v;
        }
        __syncthreads();
        bf16x8 bf0 = ((const bf16x8*)wf)[(ks * 8 + nt0) * 64 + lane];
        bf16x8 bf1 = ((const bf16x8*)wf)[(ks * 8 + nt0 + 1) * 64 + lane];
#pragma unroll
        for (int mt = 0; mt < 4; ++mt) {
            int row = mt * 16 + (lane & 15);
            float4 a0 = *(const float4*)&At[row][(lane >> 4) * 8];
            float4 a1 = *(const float4*)&At[row][(lane >> 4) * 8 + 4];
            bf16x8 af = pack8(a0, a1);
            acc[mt][0] = __builtin_amdgcn_mfma_f32_16x16x32_bf16(af, bf0, acc[mt][0], 0, 0, 0);
            acc[mt][1] = __builtin_amdgcn_mfma_f32_16x16x32_bf16(af, bf1, acc[mt][1], 0, 0, 0);
        }
    }

    const int c0 = lane & 15, rq = lane >> 4;
    float bb0 = EPI ? bias[nt0 * 16 + c0] : 0.f;
    float bb1 = EPI ? bias[nt0 * 16 + 16 + c0] : 0.f;
#pragma unroll
    for (int mt = 0; mt < 4; ++mt) {
#pragma unroll
        for (int reg = 0; reg < 4; ++reg) {
            int grow = rowBase + mt * 16 + rq * 4 + reg;
            if (grow < NN) {
                float v0 = acc[mt][0][reg], v1 = acc[mt][1][reg];
                if (EPI) {
                    float m = mask[grow];
                    v0 = fmaxf(v0 + bb0, 0.f) * m;
                    v1 = fmaxf(v1 + bb1, 0.f) * m;
                }
                out[(size_t)grow * ostride + ooff + nt0 * 16 + c0] = f2bf(v0);
                out[(size_t)grow * ostride + ooff + nt0 * 16 + 16 + c0] = f2bf(v1);
            }
        }
    }
}

// ---------------- CSR pull aggregation (bf16 h), fused bias+relu+dinv scale ----------------
template <bool BF16OUT>
__global__ __launch_bounds__(256) void gather_kernel(const int* __restrict__ off,
                                                     const int* __restrict__ cnt,
                                                     const int* __restrict__ csr_idx,
                                                     const float* __restrict__ csr_w,
                                                     const float* __restrict__ dinv,
                                                     const ushort* __restrict__ h,
                                                     const float* __restrict__ bias,
                                                     float* __restrict__ z,
                                                     ushort* __restrict__ zb,
                                                     int ostride) {
    int v = blockIdx.x * 4 + (threadIdx.x >> 6);
    if (v >= NN) return;
    int lane = threadIdx.x & 63;
    int s = off[v];
    int e = s + cnt[v];
    float accx = 0.f, accy = 0.f;
    for (; s + 3 < e; s += 4) {
        int r0 = csr_idx[s], r1 = csr_idx[s + 1], r2 = csr_idx[s + 2], r3 = csr_idx[s + 3];
        float w0 = csr_w[s], w1 = csr_w[s + 1], w2 = csr_w[s + 2], w3 = csr_w[s + 3];
        unsigned u0 = *(const unsigned*)&h[(size_t)r0 * HD + lane * 2];
        unsigned u1 = *(const unsigned*)&h[(size_t)r1 * HD + lane * 2];
        unsigned u2 = *(const unsigned*)&h[(size_t)r2 * HD + lane * 2];
        unsigned u3 = *(const unsigned*)&h[(size_t)r3 * HD + lane * 2];
        accx = fmaf(bf2f((ushort)u0), w0, accx); accy = fmaf(bf2f((ushort)(u0 >> 16)), w0, accy);
        accx = fmaf(bf2f((ushort)u1), w1, accx); accy = fmaf(bf2f((ushort)(u1 >> 16)), w1, accy);
        accx = fmaf(bf2f((ushort)u2), w2, accx); accy = fmaf(bf2f((ushort)(u2 >> 16)), w2, accy);
        accx = fmaf(bf2f((ushort)u3), w3, accx); accy = fmaf(bf2f((ushort)(u3 >> 16)), w3, accy);
    }
    for (; s < e; ++s) {
        int r0 = csr_idx[s];
        float w0 = csr_w[s];
        unsigned u0 = *(const unsigned*)&h[(size_t)r0 * HD + lane * 2];
        accx = fmaf(bf2f((ushort)u0), w0, accx); accy = fmaf(bf2f((ushort)(u0 >> 16)), w0, accy);
    }
    float dv = dinv[v];
    float2 b = *(const float2*)&bias[lane * 2];
    float ox = fmaxf(fmaf(accx, dv, b.x), 0.f);
    float oy = fmaxf(fmaf(accy, dv, b.y), 0.f);
    if (BF16OUT) {
        *(unsigned*)&zb[(size_t)v * ostride + lane * 2] = pk2bf(ox, oy);
    } else {
        float2 o; o.x = ox; o.y = oy;
        *(float2*)&z[(size_t)v * HD + lane * 2] = o;
    }
}

// ---------------- decoder: bf16 MFMA, fused pos+neg, interleaved feat rows ----------------
// block = 64 edges, 4 waves. Staging: 32 lanes read one node's full 512B feat row.
__global__ __launch_bounds__(256) void decode_mfma_kernel(const int* __restrict__ pos_edge,
                                                          const int* __restrict__ neg_edge,
                                                          const ushort* __restrict__ feat,
                                                          const ushort* __restrict__ w1f,
                                                          const float* __restrict__ b1,
                                                          const float* __restrict__ w2,
                                                          const float* __restrict__ b2,
                                                          float* __restrict__ out) {
    __shared__ ushort Flds[8 * 4 * 64 * 8];  // 32 KB, uint4-indexed, swizzled
    __shared__ int sEdge[128];
    __shared__ float part[4][64];
    const int t = threadIdx.x;
    const int w = t >> 6, lane = t & 63;
    const int bid = blockIdx.x;
    const bool isPos = bid < (NEP / 64);
    const int* edges = isPos ? pos_edge : neg_edge;
    const int ebase = (isPos ? bid : bid - NEP / 64) * 64;
    float* op = out + (isPos ? 0 : NEP);

    if (t < 128) sEdge[t] = edges[(size_t)ebase * 2 + t];
    __syncthreads();

    const int seg = t & 31, eslot = t >> 5;
#pragma unroll
    for (int it = 0; it < 8; ++it) {
        int e = it * 8 + eslot;
        int s = sEdge[2 * e], dd = sEdge[2 * e + 1];
        uint4 av = *(const uint4*)&feat[(size_t)s * FSTR + seg * 8];
        uint4 bv = *(const uint4*)&feat[(size_t)dd * FSTR + seg * 8];
        const ushort* ap = (const ushort*)&av;
        const ushort* bp = (const ushort*)&bv;
        uint4 res;
        res.x = pk2bf(bf2f(ap[0]) * bf2f(bp[0]), bf2f(ap[1]) * bf2f(bp[1]));
        res.y = pk2bf(bf2f(ap[2]) * bf2f(bp[2]), bf2f(ap[3]) * bf2f(bp[3]));
        res.z = pk2bf(bf2f(ap[4]) * bf2f(bp[4]), bf2f(ap[5]) * bf2f(bp[5]));
        res.w = pk2bf(bf2f(ap[6]) * bf2f(bp[6]), bf2f(ap[7]) * bf2f(bp[7]));
        int ks = seg >> 2;
        int mt = e >> 4;
        int fl = (e & 15) | ((seg & 3) << 4);
        int swz = (seg & 3) | ((ks & 1) << 2);
        ((uint4*)Flds)[(ks * 4 + mt) * 64 + (fl ^ swz)] = res;
    }
    __syncthreads();

    f32x4 acc[4][2] = {};
    const int nt0 = w * 2;
#pragma unroll
    for (int ks = 0; ks < 8; ++ks) {
        bf16x8 bf0 = ((const bf16x8*)w1f)[(ks * 8 + nt0) * 64 + lane];
        bf16x8 bf1 = ((const bf16x8*)w1f)[(ks * 8 + nt0 + 1) * 64 + lane];
        const int rswz = ((lane >> 4) & 3) | ((ks & 1) << 2);
#pragma unroll
        for (int mt = 0; mt < 4; ++mt) {
            bf16x8 af = ((const bf16x8*)Flds)[(ks * 4 + mt) * 64 + (lane ^ rswz)];
            acc[mt][0] = __builtin_amdgcn_mfma_f32_16x16x32_bf16(af, bf0, acc[mt][0], 0, 0, 0);
            acc[mt][1] = __builtin_amdgcn_mfma_f32_16x16x32_bf16(af, bf1, acc[mt][1], 0, 0, 0);
        }
    }

    // epilogue: hmid = relu(S + b1); partial = hmid @ w2 over this wave's 32 cols
    const int c0 = lane & 15, rq = lane >> 4;
    float b1v0 = b1[nt0 * 16 + c0], b1v1 = b1[nt0 * 16 + 16 + c0];
    float w2v0 = w2[nt0 * 16 + c0], w2v1 = w2[nt0 * 16 + 16 + c0];
#pragma unroll
    for (int mt = 0; mt < 4; ++mt) {
#pragma unroll
        for (int reg = 0; reg < 4; ++reg) {
            float h0 = fmaxf(acc[mt][0][reg] + b1v0, 0.f);
            float h1 = fmaxf(acc[mt][1][reg] + b1v1, 0.f);
            float p = fmaf(h0, w2v0, h1 * w2v1);
            p += __shfl_xor(p, 1);
            p += __shfl_xor(p, 2);
            p += __shfl_xor(p, 4);
            p += __shfl_xor(p, 8);
            if (c0 == 0) part[w][mt * 16 + rq * 4 + reg] = p;
        }
    }
    __syncthreads();
    if (t < 64) {
        op[ebase + t] = part[0][t] + part[1][t] + part[2][t] + part[3][t] + b2[0];
    }
}

extern "C" void kernel_launch(void* const* d_in, const int* in_sizes, int n_in,
                              void* d_out, int out_size, void* d_ws, size_t ws_size,
                              hipStream_t stream) {
    const int* edge_index = (const int*)d_in[0];
    const float* chemistry = (const float*)d_in[1];
    const int* pos_edge = (const int*)d_in[2];
    const int* neg_edge = (const int*)d_in[3];
    const float* smiles_mask = (const float*)d_in[4];
    const float* node_emb = (const float*)d_in[5];
    const float* conv_w = (const float*)d_in[6];
    const float* conv_b = (const float*)d_in[7];
    const float* chem_w = (const float*)d_in[8];
    const float* chem_b = (const float*)d_in[9];
    const float* dec_w1 = (const float*)d_in[10];
    const float* dec_b1 = (const float*)d_in[11];
    const float* dec_w2 = (const float*)d_in[12];
    const float* dec_b2 = (const float*)d_in[13];
    float* out = (float*)d_out;

    char* ws = (char*)d_ws;
    int* cnt = (int*)(ws + 0);
    float* dinv = (float*)(ws + 204800);
    int* partial = (int*)(ws + 409600);
    int* off = (int*)(ws + 614400);
    int* cursor = (int*)(ws + 819200);
    int* bsum = (int*)(ws + 1024000);
    int* csr_idx = (int*)(ws + 1048576);     // 4 MB
    float* csr_w = (float*)(ws + 5242880);   // 4 MB
    float* bufZ = (float*)(ws + 9437184);    // 25.6 MB (fp32 z, layer-0 out)
    ushort* hb = (ushort*)(ws + 35037184);   // 12.8 MB
    ushort* feat = (ushort*)(ws + 47837184); // 25.6 MB  [z | c] interleaved
    ushort* w1f = (ushort*)(ws + 73437184);  // 64 KB
    ushort* wcf = (ushort*)(ws + 73502720);  // 192 KB
    ushort* wc0f = (ushort*)(ws + 73699328); // 32 KB
    ushort* wc1f = (ushort*)(ws + 73732096); // 32 KB

    const int* e_row = edge_index;
    const int* e_col = edge_index + NE;

    // ---- CSR build + weight fragment packs ----
    hipMemsetAsync(cnt, 0, (size_t)NN * 4, stream);
    count_kernel<<<(NE + 255) / 256, 256, 0, stream>>>(e_col, cnt);
    dinv_kernel<<<(NN + 255) / 256, 256, 0, stream>>>(cnt, dinv);
    scan1_kernel<<<NB_SCAN, 256, 0, stream>>>(cnt, partial, bsum);
    scan2_kernel<<<1, 256, 0, stream>>>(bsum);
    scan3_kernel<<<NB_SCAN, 256, 0, stream>>>(partial, bsum, off, cursor);
    fill_kernel<<<(NE + 255) / 256, 256, 0, stream>>>(e_row, e_col, dinv, cursor, csr_idx, csr_w);
    wfrag_kernel<<<16, 256, 0, stream>>>(dec_w1, w1f);             // 8 ks
    wfrag_kernel<<<48, 256, 0, stream>>>(chem_w, wcf);             // 24 ks
    wfrag_kernel<<<8, 256, 0, stream>>>(conv_w, wc0f);             // 4 ks
    wfrag_kernel<<<8, 256, 0, stream>>>(conv_w + HD * HD, wc1f);   // 4 ks

    const int mmGrid = (NN + 63) / 64;
    const int gaGrid = (NN + 3) / 4;

    // layer 0: h = node_emb @ W0 (MFMA), then aggregate -> fp32 z
    feat_mfma_kernel<4, false><<<mmGrid, 256, 0, stream>>>(node_emb, wc0f, nullptr, nullptr, hb, HD, 0);
    gather_kernel<false><<<gaGrid, 256, 0, stream>>>(off, cnt, csr_idx, csr_w, dinv, hb, conv_b, bufZ, nullptr, 0);

    // layer 1: h = z @ W1 (MFMA), aggregate -> bf16 z into feat[:,0:128]
    feat_mfma_kernel<4, false><<<mmGrid, 256, 0, stream>>>(bufZ, wc1f, nullptr, nullptr, hb, HD, 0);
    gather_kernel<true><<<gaGrid, 256, 0, stream>>>(off, cnt, csr_idx, csr_w, dinv, hb, conv_b + HD, nullptr, feat, FSTR);

    // chemistry features -> feat[:,128:256]
    feat_mfma_kernel<24, true><<<mmGrid, 256, 0, stream>>>(chemistry, wcf, chem_b, smiles_mask, feat, FSTR, HD);

    // decode pos+neg fused
    decode_mfma_kernel<<<2 * (NEP / 64), 256, 0, stream>>>(pos_edge, neg_edge, feat, w1f,
                                                           dec_b1, dec_w2, dec_b2, out);
}

// Round 7
// 451.804 us; speedup vs baseline: 5.9867x; 1.0193x over previous
//
#include <hip/hip_runtime.h>
#include <hip/hip_fp16.h>

#define NN 50000
#define NE 1000000
#define NEP 400000
#define HD 128
#define CD 768
#define NB_SCAN 196  // ceil(NN/256)
#define FSTR 256     // feat row stride (ushorts): [z(128) | c(128)]

typedef _Float16 f16x8 __attribute__((ext_vector_type(8)));
typedef _Float16 f16x2 __attribute__((ext_vector_type(2)));
typedef __fp16 hf16x2 __attribute__((ext_vector_type(2)));
typedef __attribute__((ext_vector_type(4))) float f32x4;

__device__ __forceinline__ unsigned pk2h(float a, float b) {
    hf16x2 p = __builtin_amdgcn_cvt_pkrtz(a, b);
    return __builtin_bit_cast(unsigned, p);
}
__device__ __forceinline__ ushort f2h(float x) {
    return (ushort)(pk2h(x, 0.f) & 0xffffu);
}
__device__ __forceinline__ unsigned h2mul(unsigned a, unsigned b) {
    f16x2 ha = __builtin_bit_cast(f16x2, a);
    f16x2 hb = __builtin_bit_cast(f16x2, b);
    f16x2 r = ha * hb;
    return __builtin_bit_cast(unsigned, r);
}
__device__ __forceinline__ f16x8 pack8h(float4 a0, float4 a1) {
    union { unsigned u[4]; f16x8 v; } r;
    r.u[0] = pk2h(a0.x, a0.y);
    r.u[1] = pk2h(a0.z, a0.w);
    r.u[2] = pk2h(a1.x, a1.y);
    r.u[3] = pk2h(a1.z, a1.w);
    return r.v;
}
__device__ __forceinline__ float2 h2f2(unsigned u) {
    f16x2 h = __builtin_bit_cast(f16x2, u);
    return make_float2((float)h[0], (float)h[1]);
}

// ---------------- CSR build ----------------
__global__ __launch_bounds__(256) void count_kernel(const int* __restrict__ col,
                                                    int* __restrict__ cnt) {
    int i = blockIdx.x * 256 + threadIdx.x;
    if (i < NE) atomicAdd(&cnt[col[i]], 1);
}

__global__ __launch_bounds__(256) void dinv_kernel(const int* __restrict__ cnt,
                                                   float* __restrict__ dinv) {
    int i = blockIdx.x * 256 + threadIdx.x;
    if (i < NN) {
        int d = cnt[i];
        dinv[i] = (d > 0) ? 1.0f / sqrtf((float)d) : 0.0f;
    }
}

__global__ __launch_bounds__(256) void scan1_kernel(const int* __restrict__ cnt,
                                                    int* __restrict__ partial,
                                                    int* __restrict__ bsum) {
    __shared__ int s[256];
    int i = blockIdx.x * 256 + threadIdx.x;
    int v = (i < NN) ? cnt[i] : 0;
    s[threadIdx.x] = v;
    __syncthreads();
    for (int o = 1; o < 256; o <<= 1) {
        int t = (threadIdx.x >= o) ? s[threadIdx.x - o] : 0;
        __syncthreads();
        s[threadIdx.x] += t;
        __syncthreads();
    }
    if (i < NN) partial[i] = s[threadIdx.x] - v;
    if (threadIdx.x == 255) bsum[blockIdx.x] = s[255];
}

__global__ __launch_bounds__(256) void scan2_kernel(int* __restrict__ bsum) {
    __shared__ int s[256];
    int v = (threadIdx.x < NB_SCAN) ? bsum[threadIdx.x] : 0;
    s[threadIdx.x] = v;
    __syncthreads();
    for (int o = 1; o < 256; o <<= 1) {
        int t = (threadIdx.x >= o) ? s[threadIdx.x - o] : 0;
        __syncthreads();
        s[threadIdx.x] += t;
        __syncthreads();
    }
    if (threadIdx.x < NB_SCAN) bsum[threadIdx.x] = s[threadIdx.x] - v;
}

__global__ __launch_bounds__(256) void scan3_kernel(const int* __restrict__ partial,
                                                    const int* __restrict__ bsum,
                                                    int* __restrict__ off,
                                                    int* __restrict__ cursor) {
    int i = blockIdx.x * 256 + threadIdx.x;
    if (i < NN) {
        int o = partial[i] + bsum[blockIdx.x];
        off[i] = o;
        cursor[i] = o;
    }
}

__global__ __launch_bounds__(256) void fill_kernel(const int* __restrict__ row,
                                                   const int* __restrict__ col,
                                                   const float* __restrict__ dinv,
                                                   int* __restrict__ cursor,
                                                   int* __restrict__ csr_idx,
                                                   float* __restrict__ csr_w) {
    int e = blockIdx.x * 256 + threadIdx.x;
    if (e < NE) {
        int c = col[e], r = row[e];
        int slot = atomicAdd(&cursor[c], 1);
        csr_idx[slot] = r;
        csr_w[slot] = dinv[r];
    }
}

// ---------------- W(K x 128) -> MFMA B-fragment order, f16 ----------------
// wf[((ks*8+nt)*64 + l)*8 + j] = W[ks*32 + (l>>4)*8 + j][nt*16 + (l&15)]
__global__ __launch_bounds__(256) void wfrag_kernel(const float* __restrict__ w,
                                                    ushort* __restrict__ wf) {
    int tid = blockIdx.x * 256 + threadIdx.x;
    int ks = tid >> 9, nt = (tid >> 6) & 7, l = tid & 63;
    int kbase = ks * 32 + ((l >> 4) << 3);
    int colq = nt * 16 + (l & 15);
    ushort r[8];
#pragma unroll
    for (int j = 0; j < 8; ++j) r[j] = f2h(w[(size_t)(kbase + j) * HD + colq]);
    *(uint4*)&wf[(size_t)tid * 8] = *(uint4*)r;
}

// ---------------- MFMA matmul: out(NN x 128) = f16(A(NN x KS*32)) @ Wfrag, optional chem epilogue ----------------
template <int KS, bool EPI>
__global__ __launch_bounds__(256) void feat_mfma_kernel(const float* __restrict__ A,
                                                        const ushort* __restrict__ wf,
                                                        const float* __restrict__ bias,
                                                        const float* __restrict__ mask,
                                                        ushort* __restrict__ out,
                                                        int ostride, int ooff) {
    __shared__ float At[64][36];
    const int t = threadIdx.x;
    const int w = t >> 6, lane = t & 63;
    const int rowBase = blockIdx.x * 64;
    const int nt0 = w * 2;
    const int K = KS * 32;

    f32x4 acc[4][2] = {};

    for (int ks = 0; ks < KS; ++ks) {
        __syncthreads();
#pragma unroll
        for (int i = 0; i < 2; ++i) {
            int li = t + i * 256;           // [0,512) float4 tasks
            int r = li >> 3, c4 = li & 7;   // row, float4-col
            int grow = rowBase + r;
            float4 v = make_float4(0.f, 0.f, 0.f, 0.f);
            if (grow < NN) v = *(const float4*)&A[(size_t)grow * K + ks * 32 + c4 * 4];
            *(float4*)&At[r][c4 * 4] = v;
        }
        __syncthreads();
        f16x8 bf0 = ((const f16x8*)wf)[(ks * 8 + nt0) * 64 + lane];
        f16x8 bf1 = ((const f16x8*)wf)[(ks * 8 + nt0 + 1) * 64 + lane];
#pragma unroll
        for (int mt = 0; mt < 4; ++mt) {
            int row = mt * 16 + (lane & 15);
            float4 a0 = *(const float4*)&At[row][(lane >> 4) * 8];
            float4 a1 = *(const float4*)&At[row][(lane >> 4) * 8 + 4];
            f16x8 af = pack8h(a0, a1);
            acc[mt][0] = __builtin_amdgcn_mfma_f32_16x16x32_f16(af, bf0, acc[mt][0], 0, 0, 0);
            acc[mt][1] = __builtin_amdgcn_mfma_f32_16x16x32_f16(af, bf1, acc[mt][1], 0, 0, 0);
        }
    }

    const int c0 = lane & 15, rq = lane >> 4;
    float bb0 = EPI ? bias[nt0 * 16 + c0] : 0.f;
    float bb1 = EPI ? bias[nt0 * 16 + 16 + c0] : 0.f;
#pragma unroll
    for (int mt = 0; mt < 4; ++mt) {
#pragma unroll
        for (int reg = 0; reg < 4; ++reg) {
            int grow = rowBase + mt * 16 + rq * 4 + reg;
            if (grow < NN) {
                float v0 = acc[mt][0][reg], v1 = acc[mt][1][reg];
                if (EPI) {
                    float m = mask[grow];
                    v0 = fmaxf(v0 + bb0, 0.f) * m;
                    v1 = fmaxf(v1 + bb1, 0.f) * m;
                }
                out[(size_t)grow * ostride + ooff + nt0 * 16 + c0] = f2h(v0);
                out[(size_t)grow * ostride + ooff + nt0 * 16 + 16 + c0] = f2h(v1);
            }
        }
    }
}

// ---------------- CSR pull aggregation (f16 h), fused bias+relu+dinv scale ----------------
template <bool F16OUT>
__global__ __launch_bounds__(256) void gather_kernel(const int* __restrict__ off,
                                                     const int* __restrict__ cnt,
                                                     const int* __restrict__ csr_idx,
                                                     const float* __restrict__ csr_w,
                                                     const float* __restrict__ dinv,
                                                     const ushort* __restrict__ h,
                                                     const float* __restrict__ bias,
                                                     float* __restrict__ z,
                                                     ushort* __restrict__ zb,
                                                     int ostride) {
    int v = blockIdx.x * 4 + (threadIdx.x >> 6);
    if (v >= NN) return;
    int lane = threadIdx.x & 63;
    int s = off[v];
    int e = s + cnt[v];
    float accx = 0.f, accy = 0.f;
    for (; s + 3 < e; s += 4) {
        int r0 = csr_idx[s], r1 = csr_idx[s + 1], r2 = csr_idx[s + 2], r3 = csr_idx[s + 3];
        float w0 = csr_w[s], w1 = csr_w[s + 1], w2 = csr_w[s + 2], w3 = csr_w[s + 3];
        unsigned u0 = *(const unsigned*)&h[(size_t)r0 * HD + lane * 2];
        unsigned u1 = *(const unsigned*)&h[(size_t)r1 * HD + lane * 2];
        unsigned u2 = *(const unsigned*)&h[(size_t)r2 * HD + lane * 2];
        unsigned u3 = *(const unsigned*)&h[(size_t)r3 * HD + lane * 2];
        float2 f0 = h2f2(u0), f1 = h2f2(u1), f2 = h2f2(u2), f3 = h2f2(u3);
        accx = fmaf(f0.x, w0, accx); accy = fmaf(f0.y, w0, accy);
        accx = fmaf(f1.x, w1, accx); accy = fmaf(f1.y, w1, accy);
        accx = fmaf(f2.x, w2, accx); accy = fmaf(f2.y, w2, accy);
        accx = fmaf(f3.x, w3, accx); accy = fmaf(f3.y, w3, accy);
    }
    for (; s < e; ++s) {
        int r0 = csr_idx[s];
        float w0 = csr_w[s];
        float2 f0 = h2f2(*(const unsigned*)&h[(size_t)r0 * HD + lane * 2]);
        accx = fmaf(f0.x, w0, accx); accy = fmaf(f0.y, w0, accy);
    }
    float dv = dinv[v];
    float2 b = *(const float2*)&bias[lane * 2];
    float ox = fmaxf(fmaf(accx, dv, b.x), 0.f);
    float oy = fmaxf(fmaf(accy, dv, b.y), 0.f);
    if (F16OUT) {
        *(unsigned*)&zb[(size_t)v * ostride + lane * 2] = pk2h(ox, oy);
    } else {
        float2 o; o.x = ox; o.y = oy;
        *(float2*)&z[(size_t)v * HD + lane * 2] = o;
    }
}

// ---------------- decoder: f16 MFMA, fused pos+neg, interleaved feat rows ----------------
// block = 64 edges, 4 waves. Staging: 32 lanes read one node's full 512B feat row;
// all 16 row-loads issued before first use (MLP).
__global__ __launch_bounds__(256, 4) void decode_mfma_kernel(const int* __restrict__ pos_edge,
                                                             const int* __restrict__ neg_edge,
                                                             const ushort* __restrict__ feat,
                                                             const ushort* __restrict__ w1f,
                                                             const float* __restrict__ b1,
                                                             const float* __restrict__ w2,
                                                             const float* __restrict__ b2,
                                                             float* __restrict__ out) {
    __shared__ ushort Flds[8 * 4 * 64 * 8];  // 32 KB, uint4-indexed, swizzled
    __shared__ int sEdge[128];
    __shared__ float part[4][64];
    const int t = threadIdx.x;
    const int w = t >> 6, lane = t & 63;
    const int bid = blockIdx.x;
    const bool isPos = bid < (NEP / 64);
    const int* edges = isPos ? pos_edge : neg_edge;
    const int ebase = (isPos ? bid : bid - NEP / 64) * 64;
    float* op = out + (isPos ? 0 : NEP);

    if (t < 128) sEdge[t] = edges[(size_t)ebase * 2 + t];
    __syncthreads();

    const int seg = t & 31, eslot = t >> 5;
    uint4 avr[8], bvr[8];
#pragma unroll
    for (int it = 0; it < 8; ++it) {
        int e = it * 8 + eslot;
        int s = sEdge[2 * e], dd = sEdge[2 * e + 1];
        avr[it] = *(const uint4*)&feat[(size_t)s * FSTR + seg * 8];
        bvr[it] = *(const uint4*)&feat[(size_t)dd * FSTR + seg * 8];
    }
#pragma unroll
    for (int it = 0; it < 8; ++it) {
        int e = it * 8 + eslot;
        uint4 res;
        res.x = h2mul(avr[it].x, bvr[it].x);
        res.y = h2mul(avr[it].y, bvr[it].y);
        res.z = h2mul(avr[it].z, bvr[it].z);
        res.w = h2mul(avr[it].w, bvr[it].w);
        int ks = seg >> 2;
        int mt = e >> 4;
        int fl = (e & 15) | ((seg & 3) << 4);
        int swz = (seg & 3) | ((ks & 1) << 2);
        ((uint4*)Flds)[(ks * 4 + mt) * 64 + (fl ^ swz)] = res;
    }
    __syncthreads();

    f32x4 acc[4][2] = {};
    const int nt0 = w * 2;
#pragma unroll
    for (int ks = 0; ks < 8; ++ks) {
        f16x8 bf0 = ((const f16x8*)w1f)[(ks * 8 + nt0) * 64 + lane];
        f16x8 bf1 = ((const f16x8*)w1f)[(ks * 8 + nt0 + 1) * 64 + lane];
        const int rswz = ((lane >> 4) & 3) | ((ks & 1) << 2);
#pragma unroll
        for (int mt = 0; mt < 4; ++mt) {
            f16x8 af = ((const f16x8*)Flds)[(ks * 4 + mt) * 64 + (lane ^ rswz)];
            acc[mt][0] = __builtin_amdgcn_mfma_f32_16x16x32_f16(af, bf0, acc[mt][0], 0, 0, 0);
            acc[mt][1] = __builtin_amdgcn_mfma_f32_16x16x32_f16(af, bf1, acc[mt][1], 0, 0, 0);
        }
    }

    // epilogue: hmid = relu(S + b1); partial = hmid @ w2 over this wave's 32 cols
    const int c0 = lane & 15, rq = lane >> 4;
    float b1v0 = b1[nt0 * 16 + c0], b1v1 = b1[nt0 * 16 + 16 + c0];
    float w2v0 = w2[nt0 * 16 + c0], w2v1 = w2[nt0 * 16 + 16 + c0];
#pragma unroll
    for (int mt = 0; mt < 4; ++mt) {
#pragma unroll
        for (int reg = 0; reg < 4; ++reg) {
            float h0 = fmaxf(acc[mt][0][reg] + b1v0, 0.f);
            float h1 = fmaxf(acc[mt][1][reg] + b1v1, 0.f);
            float p = fmaf(h0, w2v0, h1 * w2v1);
            p += __shfl_xor(p, 1);
            p += __shfl_xor(p, 2);
            p += __shfl_xor(p, 4);
            p += __shfl_xor(p, 8);
            if (c0 == 0) part[w][mt * 16 + rq * 4 + reg] = p;
        }
    }
    __syncthreads();
    if (t < 64) {
        op[ebase + t] = part[0][t] + part[1][t] + part[2][t] + part[3][t] + b2[0];
    }
}

extern "C" void kernel_launch(void* const* d_in, const int* in_sizes, int n_in,
                              void* d_out, int out_size, void* d_ws, size_t ws_size,
                              hipStream_t stream) {
    const int* edge_index = (const int*)d_in[0];
    const float* chemistry = (const float*)d_in[1];
    const int* pos_edge = (const int*)d_in[2];
    const int* neg_edge = (const int*)d_in[3];
    const float* smiles_mask = (const float*)d_in[4];
    const float* node_emb = (const float*)d_in[5];
    const float* conv_w = (const float*)d_in[6];
    const float* conv_b = (const float*)d_in[7];
    const float* chem_w = (const float*)d_in[8];
    const float* chem_b = (const float*)d_in[9];
    const float* dec_w1 = (const float*)d_in[10];
    const float* dec_b1 = (const float*)d_in[11];
    const float* dec_w2 = (const float*)d_in[12];
    const float* dec_b2 = (const float*)d_in[13];
    float* out = (float*)d_out;

    char* ws = (char*)d_ws;
    int* cnt = (int*)(ws + 0);
    float* dinv = (float*)(ws + 204800);
    int* partial = (int*)(ws + 409600);
    int* off = (int*)(ws + 614400);
    int* cursor = (int*)(ws + 819200);
    int* bsum = (int*)(ws + 1024000);
    int* csr_idx = (int*)(ws + 1048576);     // 4 MB
    float* csr_w = (float*)(ws + 5242880);   // 4 MB
    float* bufZ = (float*)(ws + 9437184);    // 25.6 MB (fp32 z, layer-0 out)
    ushort* hb = (ushort*)(ws + 35037184);   // 12.8 MB
    ushort* feat = (ushort*)(ws + 47837184); // 25.6 MB  [z | c] interleaved
    ushort* w1f = (ushort*)(ws + 73437184);  // 64 KB
    ushort* wcf = (ushort*)(ws + 73502720);  // 192 KB
    ushort* wc0f = (ushort*)(ws + 73699328); // 32 KB
    ushort* wc1f = (ushort*)(ws + 73732096); // 32 KB

    const int* e_row = edge_index;
    const int* e_col = edge_index + NE;

    // ---- CSR build + weight fragment packs ----
    hipMemsetAsync(cnt, 0, (size_t)NN * 4, stream);
    count_kernel<<<(NE + 255) / 256, 256, 0, stream>>>(e_col, cnt);
    dinv_kernel<<<(NN + 255) / 256, 256, 0, stream>>>(cnt, dinv);
    scan1_kernel<<<NB_SCAN, 256, 0, stream>>>(cnt, partial, bsum);
    scan2_kernel<<<1, 256, 0, stream>>>(bsum);
    scan3_kernel<<<NB_SCAN, 256, 0, stream>>>(partial, bsum, off, cursor);
    fill_kernel<<<(NE + 255) / 256, 256, 0, stream>>>(e_row, e_col, dinv, cursor, csr_idx, csr_w);
    wfrag_kernel<<<16, 256, 0, stream>>>(dec_w1, w1f);             // 8 ks
    wfrag_kernel<<<48, 256, 0, stream>>>(chem_w, wcf);             // 24 ks
    wfrag_kernel<<<8, 256, 0, stream>>>(conv_w, wc0f);             // 4 ks
    wfrag_kernel<<<8, 256, 0, stream>>>(conv_w + HD * HD, wc1f);   // 4 ks

    const int mmGrid = (NN + 63) / 64;
    const int gaGrid = (NN + 3) / 4;

    // layer 0: h = node_emb @ W0 (MFMA), then aggregate -> fp32 z
    feat_mfma_kernel<4, false><<<mmGrid, 256, 0, stream>>>(node_emb, wc0f, nullptr, nullptr, hb, HD, 0);
    gather_kernel<false><<<gaGrid, 256, 0, stream>>>(off, cnt, csr_idx, csr_w, dinv, hb, conv_b, bufZ, nullptr, 0);

    // layer 1: h = z @ W1 (MFMA), aggregate -> f16 z into feat[:,0:128]
    feat_mfma_kernel<4, false><<<mmGrid, 256, 0, stream>>>(bufZ, wc1f, nullptr, nullptr, hb, HD, 0);
    gather_kernel<true><<<gaGrid, 256, 0, stream>>>(off, cnt, csr_idx, csr_w, dinv, hb, conv_b + HD, nullptr, feat, FSTR);

    // chemistry features -> feat[:,128:256]
    feat_mfma_kernel<24, true><<<mmGrid, 256, 0, stream>>>(chemistry, wcf, chem_b, smiles_mask, feat, FSTR, HD);

    // decode pos+neg fused
    decode_mfma_kernel<<<2 * (NEP / 64), 256, 0, stream>>>(pos_edge, neg_edge, feat, w1f,
                                                           dec_b1, dec_w2, dec_b2, out);
}